// Round 1
// baseline (505.759 us; speedup 1.0000x reference)
//
#include <hip/hip_runtime.h>
#include <hip/hip_bf16.h>

#define NTOK 8192
#define CDIM 1024
#define FDIM 1024
#define NEXP 8

typedef __attribute__((ext_vector_type(8))) short short8;
typedef __attribute__((ext_vector_type(4))) float f32x4;

union Pack8 { __hip_bfloat16 h[8]; short8 v; };
union Pack4 { __hip_bfloat16 h[4]; unsigned long long v; };

// ---------------- router: logits -> softmax -> top2 -> scatter ----------------
__global__ __launch_bounds__(256) void router_kernel(
    const float* __restrict__ x, const float* __restrict__ rw,
    int* __restrict__ cnt, int* __restrict__ rows, float* __restrict__ wts)
{
    const int wv = threadIdx.x >> 6, lane = threadIdx.x & 63;
    const int n = blockIdx.x * 4 + wv;
    float acc[NEXP];
#pragma unroll
    for (int e = 0; e < NEXP; e++) acc[e] = 0.f;
    for (int c0 = 0; c0 < CDIM; c0 += 64) {
        float xv = x[(size_t)n * CDIM + c0 + lane];
#pragma unroll
        for (int e = 0; e < NEXP; e++) acc[e] += xv * rw[e * CDIM + c0 + lane];
    }
#pragma unroll
    for (int e = 0; e < NEXP; e++) {
#pragma unroll
        for (int s = 32; s > 0; s >>= 1) acc[e] += __shfl_xor(acc[e], s);
    }
    if (lane == 0) {
        float mx = acc[0];
#pragma unroll
        for (int e = 1; e < NEXP; e++) mx = fmaxf(mx, acc[e]);
        float p[NEXP], se = 0.f;
#pragma unroll
        for (int e = 0; e < NEXP; e++) { p[e] = __expf(acc[e] - mx); se += p[e]; }
        float inv = 1.f / se;
        int i0 = 0;
#pragma unroll
        for (int e = 1; e < NEXP; e++) if (p[e] > p[i0]) i0 = e;
        int i1 = (i0 == 0) ? 1 : 0;
#pragma unroll
        for (int e = 0; e < NEXP; e++) if (e != i0 && p[e] > p[i1]) i1 = e;
        int pos0 = atomicAdd(&cnt[i0], 1);
        rows[i0 * NTOK + pos0] = n; wts[i0 * NTOK + pos0] = p[i0] * inv;
        int pos1 = atomicAdd(&cnt[i1], 1);
        rows[i1 * NTOK + pos1] = n; wts[i1 * NTOK + pos1] = p[i1] * inv;
    }
}

__global__ void scan_offsets(const int* __restrict__ cnt, int* __restrict__ offs)
{
    if (threadIdx.x == 0) {
        int s = 0;
        for (int e = 0; e < NEXP; e++) { offs[e] = s; s += cnt[e]; }
    }
}

// ------------- transpose + fp32->bf16: src [E][R][C] -> dst [E][C][R] -------------
__global__ __launch_bounds__(256) void transpose_conv(
    const float* __restrict__ src, __hip_bfloat16* __restrict__ dst)
{
    __shared__ float t[32][33];
    const int e = blockIdx.z;
    const int r0 = blockIdx.x * 32, c0 = blockIdx.y * 32;
    const int tid = threadIdx.x;
    const int rr = tid >> 3;
    const int cc = (tid & 7) * 4;
    const float* p = src + ((size_t)e * 1024 + r0 + rr) * 1024 + c0 + cc;
    float4 v = *(const float4*)p;
    t[rr][cc] = v.x; t[rr][cc + 1] = v.y; t[rr][cc + 2] = v.z; t[rr][cc + 3] = v.w;
    __syncthreads();
    const int cr = tid >> 3;
    const int rc = (tid & 7) * 4;
    Pack4 o;
#pragma unroll
    for (int j = 0; j < 4; j++) o.h[j] = __float2bfloat16(t[rc + j][cr]);
    *(unsigned long long*)(dst + ((size_t)e * 1024 + c0 + cr) * 1024 + r0 + rc) = o.v;
}

// ---------------- GEMM1: hid = relu(X[rows] @ w1t^T) ----------------
// w1t: [E][FDIM][CDIM] bf16 (n-major, k contiguous)
__global__ __launch_bounds__(256) void moe_gemm1(
    const float* __restrict__ x, const __hip_bfloat16* __restrict__ w1t,
    const int* __restrict__ cnt, const int* __restrict__ offs,
    const int* __restrict__ rows, __hip_bfloat16* __restrict__ hid)
{
    const int e = blockIdx.y;
    const int me = cnt[e];
    const int m0 = blockIdx.x * 64;
    if (m0 >= me) return;
    const int n0 = blockIdx.z * 64;
    const int off = offs[e];
    const int tid = threadIdx.x;
    const int lane = tid & 63, wv = tid >> 6;

    __shared__ alignas(16) __hip_bfloat16 Al[64][40];
    __shared__ alignas(16) __hip_bfloat16 Bl[64][40];
    __shared__ int rtok[64];

    if (tid < 64) {
        int i = m0 + tid;
        rtok[tid] = (i < me) ? rows[e * NTOK + i] : -1;
    }
    __syncthreads();

    f32x4 acc[4] = {};
    const int srow = tid >> 2;
    const int sk8 = (tid & 3) * 8;
    const int fr = lane & 15, fq = lane >> 4;

    for (int k0 = 0; k0 < CDIM; k0 += 32) {
        // stage A (gathered x rows, fp32 -> bf16)
        {
            int tok = rtok[srow];
            float4 v0 = {0, 0, 0, 0}, v1 = {0, 0, 0, 0};
            if (tok >= 0) {
                const float* p = x + (size_t)tok * CDIM + k0 + sk8;
                v0 = *(const float4*)p;
                v1 = *(const float4*)(p + 4);
            }
            Pack8 pk;
            pk.h[0] = __float2bfloat16(v0.x); pk.h[1] = __float2bfloat16(v0.y);
            pk.h[2] = __float2bfloat16(v0.z); pk.h[3] = __float2bfloat16(v0.w);
            pk.h[4] = __float2bfloat16(v1.x); pk.h[5] = __float2bfloat16(v1.y);
            pk.h[6] = __float2bfloat16(v1.z); pk.h[7] = __float2bfloat16(v1.w);
            *(short8*)&Al[srow][sk8] = pk.v;
        }
        // stage B
        {
            const __hip_bfloat16* p =
                w1t + ((size_t)e * FDIM + n0 + srow) * CDIM + k0 + sk8;
            *(short8*)&Bl[srow][sk8] = *(const short8*)p;
        }
        __syncthreads();
        short8 af = *(const short8*)&Al[wv * 16 + fr][fq * 8];
#pragma unroll
        for (int ns = 0; ns < 4; ns++) {
            short8 bf = *(const short8*)&Bl[ns * 16 + fr][fq * 8];
            acc[ns] = __builtin_amdgcn_mfma_f32_16x16x32_bf16(af, bf, acc[ns], 0, 0, 0);
        }
        __syncthreads();
    }

#pragma unroll
    for (int ns = 0; ns < 4; ns++) {
#pragma unroll
        for (int r = 0; r < 4; r++) {
            int il = wv * 16 + 4 * fq + r;
            int gi = m0 + il;
            if (gi < me) {
                float v = acc[ns][r];
                v = v > 0.f ? v : 0.f;
                hid[(size_t)(off + gi) * FDIM + n0 + ns * 16 + fr] = __float2bfloat16(v);
            }
        }
    }
}

// ---------------- GEMM2: out[tok] += wt * (hid @ w2t^T) ----------------
__global__ __launch_bounds__(256) void moe_gemm2(
    const __hip_bfloat16* __restrict__ hid, const __hip_bfloat16* __restrict__ w2t,
    const int* __restrict__ cnt, const int* __restrict__ offs,
    const int* __restrict__ rows, const float* __restrict__ wts,
    float* __restrict__ out)
{
    const int e = blockIdx.y;
    const int me = cnt[e];
    const int m0 = blockIdx.x * 64;
    if (m0 >= me) return;
    const int n0 = blockIdx.z * 64;
    const int off = offs[e];
    const int tid = threadIdx.x;
    const int lane = tid & 63, wv = tid >> 6;

    __shared__ alignas(16) __hip_bfloat16 Al[64][40];
    __shared__ alignas(16) __hip_bfloat16 Bl[64][40];
    __shared__ int rtok[64];
    __shared__ float rwt[64];

    if (tid < 64) {
        int i = m0 + tid;
        rtok[tid] = (i < me) ? rows[e * NTOK + i] : -1;
        rwt[tid] = (i < me) ? wts[e * NTOK + i] : 0.f;
    }
    __syncthreads();

    f32x4 acc[4] = {};
    const int srow = tid >> 2;
    const int sk8 = (tid & 3) * 8;
    const int fr = lane & 15, fq = lane >> 4;

    for (int k0 = 0; k0 < FDIM; k0 += 32) {
        {
            short8 v = {};
            int i = m0 + srow;
            if (i < me)
                v = *(const short8*)(hid + (size_t)(off + i) * FDIM + k0 + sk8);
            *(short8*)&Al[srow][sk8] = v;
        }
        {
            const __hip_bfloat16* p =
                w2t + ((size_t)e * CDIM + n0 + srow) * FDIM + k0 + sk8;
            *(short8*)&Bl[srow][sk8] = *(const short8*)p;
        }
        __syncthreads();
        short8 af = *(const short8*)&Al[wv * 16 + fr][fq * 8];
#pragma unroll
        for (int ns = 0; ns < 4; ns++) {
            short8 bf = *(const short8*)&Bl[ns * 16 + fr][fq * 8];
            acc[ns] = __builtin_amdgcn_mfma_f32_16x16x32_bf16(af, bf, acc[ns], 0, 0, 0);
        }
        __syncthreads();
    }

#pragma unroll
    for (int ns = 0; ns < 4; ns++) {
#pragma unroll
        for (int r = 0; r < 4; r++) {
            int il = wv * 16 + 4 * fq + r;
            int gi = m0 + il;
            if (gi < me) {
                int tok = rtok[il];
                float wt = rwt[il];
                atomicAdd(&out[(size_t)tok * CDIM + n0 + ns * 16 + fr], wt * acc[ns][r]);
            }
        }
    }
}

// ---------------- launch ----------------
extern "C" void kernel_launch(void* const* d_in, const int* in_sizes, int n_in,
                              void* d_out, int out_size, void* d_ws, size_t ws_size,
                              hipStream_t stream)
{
    const float* x  = (const float*)d_in[0];
    const float* rw = (const float*)d_in[1];
    const float* w1 = (const float*)d_in[2];
    const float* w2 = (const float*)d_in[3];
    float* out = (float*)d_out;
    char* ws = (char*)d_ws;

    int* cnt  = (int*)ws;                       // 8 ints
    int* offs = (int*)(ws + 64);                // 8 ints
    int* rows = (int*)(ws + 128);               // [E][NTOK]
    float* wts = (float*)(ws + 128 + NEXP * NTOK * 4);
    __hip_bfloat16* w1t = (__hip_bfloat16*)(ws + (1 << 20));
    __hip_bfloat16* w2t = (__hip_bfloat16*)(ws + (1 << 20) + (16u << 20));
    __hip_bfloat16* hid = (__hip_bfloat16*)(ws + (1 << 20) + (32u << 20));

    hipMemsetAsync(cnt, 0, 64, stream);
    hipMemsetAsync(d_out, 0, (size_t)out_size * sizeof(float), stream);

    router_kernel<<<NTOK / 4, 256, 0, stream>>>(x, rw, cnt, rows, wts);
    scan_offsets<<<1, 64, 0, stream>>>(cnt, offs);
    transpose_conv<<<dim3(32, 32, NEXP), 256, 0, stream>>>(w1, w1t);
    transpose_conv<<<dim3(32, 32, NEXP), 256, 0, stream>>>(w2, w2t);
    moe_gemm1<<<dim3(NTOK / 64, NEXP, FDIM / 64), 256, 0, stream>>>(
        x, w1t, cnt, offs, rows, hid);
    moe_gemm2<<<dim3(NTOK / 64, NEXP, CDIM / 64), 256, 0, stream>>>(
        hid, w2t, cnt, offs, rows, wts, out);
}

// Round 2
// 330.513 us; speedup vs baseline: 1.5302x; 1.5302x over previous
//
#include <hip/hip_runtime.h>
#include <hip/hip_bf16.h>

#define NTOK 8192
#define CDIM 1024
#define FDIM 1024
#define NEXP 8
#define BM 128
#define BN 128
#define BK 64

typedef __attribute__((ext_vector_type(8))) short short8;
typedef __attribute__((ext_vector_type(4))) float f32x4;

union Pack8 { __hip_bfloat16 h[8]; short8 v; };
union Pack4 { __hip_bfloat16 h[4]; unsigned long long v; };

typedef const unsigned int __attribute__((address_space(1)))* gas_ptr;
typedef unsigned int __attribute__((address_space(3)))* las_ptr;

// async global->LDS, 16B per lane, dest = wave-uniform base + lane*16
__device__ __forceinline__ void gload16(const void* g, void* l) {
    __builtin_amdgcn_global_load_lds(
        (gas_ptr)(unsigned long long)g,
        (las_ptr)(unsigned int)(unsigned long long)l,
        16, 0, 0);
}

// ---------------- router: LDS-aggregated top-2 scatter ----------------
// 512 blocks x 16 tokens. Global counters padded to 64B stride.
__global__ __launch_bounds__(256) void router_kernel(
    const float* __restrict__ x, const float* __restrict__ rw,
    int* __restrict__ cnt, int* __restrict__ rows, float* __restrict__ wts)
{
    __shared__ int lcnt[NEXP];
    __shared__ int lt[NEXP][32];
    __shared__ float lw[NEXP][32];
    __shared__ int base[NEXP];
    const int tid = threadIdx.x;
    const int wv = tid >> 6, lane = tid & 63;
    if (tid < NEXP) lcnt[tid] = 0;
    __syncthreads();

    for (int tt = 0; tt < 4; tt++) {
        const int n = blockIdx.x * 16 + wv * 4 + tt;
        float acc[NEXP];
#pragma unroll
        for (int e = 0; e < NEXP; e++) acc[e] = 0.f;
#pragma unroll 4
        for (int c0 = 0; c0 < CDIM; c0 += 64) {
            float xv = x[(size_t)n * CDIM + c0 + lane];
#pragma unroll
            for (int e = 0; e < NEXP; e++) acc[e] += xv * rw[e * CDIM + c0 + lane];
        }
#pragma unroll
        for (int e = 0; e < NEXP; e++) {
#pragma unroll
            for (int s = 32; s > 0; s >>= 1) acc[e] += __shfl_xor(acc[e], s);
        }
        if (lane == 0) {
            float mx = acc[0];
#pragma unroll
            for (int e = 1; e < NEXP; e++) mx = fmaxf(mx, acc[e]);
            float p[NEXP], se = 0.f;
#pragma unroll
            for (int e = 0; e < NEXP; e++) { p[e] = __expf(acc[e] - mx); se += p[e]; }
            float inv = 1.f / se;
            int i0 = 0;
#pragma unroll
            for (int e = 1; e < NEXP; e++) if (p[e] > p[i0]) i0 = e;
            int i1 = (i0 == 0) ? 1 : 0;
#pragma unroll
            for (int e = 0; e < NEXP; e++) if (e != i0 && p[e] > p[i1]) i1 = e;
            int p0 = atomicAdd(&lcnt[i0], 1);
            lt[i0][p0] = n; lw[i0][p0] = p[i0] * inv;
            int p1 = atomicAdd(&lcnt[i1], 1);
            lt[i1][p1] = n; lw[i1][p1] = p[i1] * inv;
        }
    }
    __syncthreads();
    if (tid < NEXP) base[tid] = atomicAdd(&cnt[tid * 16], lcnt[tid]);
    __syncthreads();
#pragma unroll
    for (int e = 0; e < NEXP; e++) {
        for (int i = tid; i < lcnt[e]; i += 256) {
            rows[e * NTOK + base[e] + i] = lt[e][i];
            wts [e * NTOK + base[e] + i] = lw[e][i];
        }
    }
}

__global__ void scan_offsets(const int* __restrict__ cnt, int* __restrict__ offs)
{
    if (threadIdx.x == 0) {
        int s = 0;
        for (int e = 0; e < NEXP; e++) { offs[e] = s; s += cnt[e * 16]; }
    }
}

// ------------- transpose + fp32->bf16: src [E][R][C] -> dst [E][C][R] -------------
__global__ __launch_bounds__(256) void transpose_conv(
    const float* __restrict__ src, __hip_bfloat16* __restrict__ dst)
{
    __shared__ float t[32][33];
    const int e = blockIdx.z;
    const int r0 = blockIdx.x * 32, c0 = blockIdx.y * 32;
    const int tid = threadIdx.x;
    const int rr = tid >> 3;
    const int cc = (tid & 7) * 4;
    const float* p = src + ((size_t)e * 1024 + r0 + rr) * 1024 + c0 + cc;
    float4 v = *(const float4*)p;
    t[rr][cc] = v.x; t[rr][cc + 1] = v.y; t[rr][cc + 2] = v.z; t[rr][cc + 3] = v.w;
    __syncthreads();
    const int cr = tid >> 3;
    const int rc = (tid & 7) * 4;
    Pack4 o;
#pragma unroll
    for (int j = 0; j < 4; j++) o.h[j] = __float2bfloat16(t[rc + j][cr]);
    *(unsigned long long*)(dst + ((size_t)e * 1024 + c0 + cr) * 1024 + r0 + rc) = o.v;
}

// ---------------- GEMM1: hid = relu(X[rows] @ w1t^T), 128x128 tile ----------------
__global__ __launch_bounds__(256) void moe_gemm1(
    const float* __restrict__ x, const __hip_bfloat16* __restrict__ w1t,
    const int* __restrict__ cnt, const int* __restrict__ offs,
    const int* __restrict__ rows, __hip_bfloat16* __restrict__ hid)
{
    const int e = blockIdx.y;
    const int me = cnt[e * 16];
    const int m0 = blockIdx.x * BM;
    if (m0 >= me) return;
    const int n0 = blockIdx.z * BN;
    const int off = offs[e];
    const int tid = threadIdx.x;
    const int lane = tid & 63, wv = tid >> 6;
    const int wr = wv >> 1, wc = wv & 1;
    const int fr = lane & 15, fq = lane >> 4;

    __shared__ alignas(16) __hip_bfloat16 Al[BM][BK];
    __shared__ alignas(16) __hip_bfloat16 Bl[BN][BK];

    // A reg-stage setup: each thread owns 4 16B chunks (row rb+32i, cols c8..c8+7)
    const int c8 = (tid & 7) * 8;
    const int rb = tid >> 3;
    const float* ap[4];
#pragma unroll
    for (int i = 0; i < 4; i++) {
        int gi = m0 + rb + i * 32;
        int ri = gi < me ? gi : me - 1;
        int tok = rows[e * NTOK + ri];
        ap[i] = x + (size_t)tok * CDIM + c8;
    }
    // B gload setup: wave stages rows wv*32..wv*32+31
    const int bcol = (lane & 7) * 8;
    const int brow8 = lane >> 3;
    const __hip_bfloat16* bsrc[4];
#pragma unroll
    for (int i = 0; i < 4; i++)
        bsrc[i] = w1t + ((size_t)e * FDIM + n0 + wv * 32 + i * 8 + brow8) * CDIM + bcol;

    f32x4 acc[4][4] = {};

    for (int k0 = 0; k0 < CDIM; k0 += BK) {
#pragma unroll
        for (int i = 0; i < 4; i++) {
            float4 v0 = *(const float4*)(ap[i] + k0);
            float4 v1 = *(const float4*)(ap[i] + k0 + 4);
            Pack8 pk;
            pk.h[0] = __float2bfloat16(v0.x); pk.h[1] = __float2bfloat16(v0.y);
            pk.h[2] = __float2bfloat16(v0.z); pk.h[3] = __float2bfloat16(v0.w);
            pk.h[4] = __float2bfloat16(v1.x); pk.h[5] = __float2bfloat16(v1.y);
            pk.h[6] = __float2bfloat16(v1.z); pk.h[7] = __float2bfloat16(v1.w);
            *(short8*)&Al[rb + i * 32][c8] = pk.v;
        }
#pragma unroll
        for (int i = 0; i < 4; i++)
            gload16(bsrc[i] + k0, &Bl[wv * 32 + i * 8][0]);
        __syncthreads();
#pragma unroll
        for (int ks = 0; ks < 2; ks++) {
            short8 af[4], bfv[4];
#pragma unroll
            for (int m = 0; m < 4; m++)
                af[m] = *(const short8*)&Al[wr * 64 + m * 16 + fr][ks * 32 + fq * 8];
#pragma unroll
            for (int n = 0; n < 4; n++)
                bfv[n] = *(const short8*)&Bl[wc * 64 + n * 16 + fr][ks * 32 + fq * 8];
#pragma unroll
            for (int m = 0; m < 4; m++)
#pragma unroll
                for (int n = 0; n < 4; n++)
                    acc[m][n] = __builtin_amdgcn_mfma_f32_16x16x32_bf16(
                        af[m], bfv[n], acc[m][n], 0, 0, 0);
        }
        __syncthreads();
    }

#pragma unroll
    for (int m = 0; m < 4; m++) {
#pragma unroll
        for (int n = 0; n < 4; n++) {
#pragma unroll
            for (int r = 0; r < 4; r++) {
                int il = wr * 64 + m * 16 + fq * 4 + r;
                int gi = m0 + il;
                if (gi < me) {
                    float v = acc[m][n][r];
                    v = v > 0.f ? v : 0.f;
                    hid[(size_t)(off + gi) * FDIM + n0 + wc * 64 + n * 16 + fr] =
                        __float2bfloat16(v);
                }
            }
        }
    }
}

// ---------------- GEMM2: out[tok] += wt * (hid @ w2t^T), 128x128 tile ----------------
__global__ __launch_bounds__(256) void moe_gemm2(
    const __hip_bfloat16* __restrict__ hid, const __hip_bfloat16* __restrict__ w2t,
    const int* __restrict__ cnt, const int* __restrict__ offs,
    const int* __restrict__ rows, const float* __restrict__ wts,
    float* __restrict__ out)
{
    const int e = blockIdx.y;
    const int me = cnt[e * 16];
    const int m0 = blockIdx.x * BM;
    if (m0 >= me) return;
    const int n0 = blockIdx.z * BN;
    const int off = offs[e];
    const int tid = threadIdx.x;
    const int lane = tid & 63, wv = tid >> 6;
    const int wr = wv >> 1, wc = wv & 1;
    const int fr = lane & 15, fq = lane >> 4;

    __shared__ alignas(16) __hip_bfloat16 Al[BM][BK];
    __shared__ alignas(16) __hip_bfloat16 Bl[BN][BK];
    __shared__ int rtok[BM];
    __shared__ float rwt[BM];

    if (tid < BM) {
        int gi = m0 + tid;
        int ri = gi < me ? gi : me - 1;
        rtok[tid] = rows[e * NTOK + ri];
        rwt[tid] = gi < me ? wts[e * NTOK + ri] : 0.f;
    }

    const int bcol = (lane & 7) * 8;
    const int brow8 = lane >> 3;
    const __hip_bfloat16* asrc[4];
    const __hip_bfloat16* bsrc[4];
#pragma unroll
    for (int i = 0; i < 4; i++) {
        int gi = m0 + wv * 32 + i * 8 + brow8;
        int ri = gi < me ? gi : me - 1;
        asrc[i] = hid + (size_t)(off + ri) * FDIM + bcol;
        bsrc[i] = w2t + ((size_t)e * CDIM + n0 + wv * 32 + i * 8 + brow8) * FDIM + bcol;
    }

    f32x4 acc[4][4] = {};

    for (int k0 = 0; k0 < FDIM; k0 += BK) {
#pragma unroll
        for (int i = 0; i < 4; i++) {
            gload16(asrc[i] + k0, &Al[wv * 32 + i * 8][0]);
            gload16(bsrc[i] + k0, &Bl[wv * 32 + i * 8][0]);
        }
        __syncthreads();
#pragma unroll
        for (int ks = 0; ks < 2; ks++) {
            short8 af[4], bfv[4];
#pragma unroll
            for (int m = 0; m < 4; m++)
                af[m] = *(const short8*)&Al[wr * 64 + m * 16 + fr][ks * 32 + fq * 8];
#pragma unroll
            for (int n = 0; n < 4; n++)
                bfv[n] = *(const short8*)&Bl[wc * 64 + n * 16 + fr][ks * 32 + fq * 8];
#pragma unroll
            for (int m = 0; m < 4; m++)
#pragma unroll
                for (int n = 0; n < 4; n++)
                    acc[m][n] = __builtin_amdgcn_mfma_f32_16x16x32_bf16(
                        af[m], bfv[n], acc[m][n], 0, 0, 0);
        }
        __syncthreads();
    }

#pragma unroll
    for (int m = 0; m < 4; m++) {
#pragma unroll
        for (int n = 0; n < 4; n++) {
#pragma unroll
            for (int r = 0; r < 4; r++) {
                int il = wr * 64 + m * 16 + fq * 4 + r;
                int gi = m0 + il;
                if (gi < me) {
                    atomicAdd(&out[(size_t)rtok[il] * CDIM + n0 + wc * 64 + n * 16 + fr],
                              rwt[il] * acc[m][n][r]);
                }
            }
        }
    }
}

// ---------------- launch ----------------
extern "C" void kernel_launch(void* const* d_in, const int* in_sizes, int n_in,
                              void* d_out, int out_size, void* d_ws, size_t ws_size,
                              hipStream_t stream)
{
    const float* x  = (const float*)d_in[0];
    const float* rw = (const float*)d_in[1];
    const float* w1 = (const float*)d_in[2];
    const float* w2 = (const float*)d_in[3];
    float* out = (float*)d_out;
    char* ws = (char*)d_ws;

    int* cnt  = (int*)ws;                         // 8 counters, stride 16 ints (64B)
    int* offs = (int*)(ws + 1024);
    int* rows = (int*)(ws + 4096);                // [E][NTOK] int
    float* wts = (float*)(ws + 4096 + NEXP * NTOK * 4);
    __hip_bfloat16* w1t = (__hip_bfloat16*)(ws + (1u << 20));          // 16 MB
    __hip_bfloat16* w2t = (__hip_bfloat16*)(ws + (1u << 20) + (16u << 20));
    __hip_bfloat16* hid = (__hip_bfloat16*)(ws + (1u << 20) + (32u << 20)); // 32 MB

    hipMemsetAsync(cnt, 0, 1024, stream);
    hipMemsetAsync(d_out, 0, (size_t)out_size * sizeof(float), stream);

    router_kernel<<<NTOK / 16, 256, 0, stream>>>(x, rw, cnt, rows, wts);
    scan_offsets<<<1, 64, 0, stream>>>(cnt, offs);
    transpose_conv<<<dim3(32, 32, NEXP), 256, 0, stream>>>(w1, w1t);
    transpose_conv<<<dim3(32, 32, NEXP), 256, 0, stream>>>(w2, w2t);
    moe_gemm1<<<dim3(NTOK / BM, NEXP, FDIM / BN), 256, 0, stream>>>(
        x, w1t, cnt, offs, rows, hid);
    moe_gemm2<<<dim3(NTOK / BM, NEXP, CDIM / BN), 256, 0, stream>>>(
        hid, w2t, cnt, offs, rows, wts, out);
}

// Round 3
// 253.128 us; speedup vs baseline: 1.9980x; 1.3057x over previous
//
#include <hip/hip_runtime.h>
#include <hip/hip_bf16.h>

#define NTOK 8192
#define CDIM 1024
#define FDIM 1024
#define NEXP 8
#define BM 128
#define BN 128
#define BK 64
#define MAXT 136   // sum ceil(me/BM) <= 2*NTOK/BM + NEXP

typedef __attribute__((ext_vector_type(8))) short short8;
typedef __attribute__((ext_vector_type(4))) float f32x4;

union Pack8 { __hip_bfloat16 h[8]; short8 v; };
union Pack4 { __hip_bfloat16 h[4]; unsigned long long v; };

typedef const unsigned int __attribute__((address_space(1)))* gas_ptr;
typedef unsigned int __attribute__((address_space(3)))* las_ptr;

// async global->LDS: per-lane global src, dest = wave-uniform base + lane*16
__device__ __forceinline__ void gload16(const void* g, void* l) {
    __builtin_amdgcn_global_load_lds(
        (gas_ptr)(unsigned long long)g,
        (las_ptr)(unsigned int)(unsigned long long)l,
        16, 0, 0);
}

// ---------------- router: float4 dot + LDS-aggregated top-2 scatter ----------------
__global__ __launch_bounds__(256) void router_kernel(
    const float* __restrict__ x, const float* __restrict__ rw,
    int* __restrict__ cnt, int* __restrict__ rows, float* __restrict__ wts)
{
    __shared__ int lcnt[NEXP];
    __shared__ int lt[NEXP][32];
    __shared__ float lw[NEXP][32];
    __shared__ int base[NEXP];
    const int tid = threadIdx.x;
    const int wv = tid >> 6, lane = tid & 63;
    if (tid < NEXP) lcnt[tid] = 0;
    __syncthreads();

    for (int tt = 0; tt < 4; tt++) {
        const int n = blockIdx.x * 16 + wv * 4 + tt;
        float acc[NEXP];
#pragma unroll
        for (int e = 0; e < NEXP; e++) acc[e] = 0.f;
#pragma unroll
        for (int c0 = 0; c0 < CDIM; c0 += 256) {
            float4 xv = *(const float4*)&x[(size_t)n * CDIM + c0 + lane * 4];
#pragma unroll
            for (int e = 0; e < NEXP; e++) {
                float4 wv4 = *(const float4*)&rw[e * CDIM + c0 + lane * 4];
                acc[e] += xv.x * wv4.x + xv.y * wv4.y + xv.z * wv4.z + xv.w * wv4.w;
            }
        }
#pragma unroll
        for (int e = 0; e < NEXP; e++) {
#pragma unroll
            for (int s = 32; s > 0; s >>= 1) acc[e] += __shfl_xor(acc[e], s);
        }
        if (lane == 0) {
            float mx = acc[0];
#pragma unroll
            for (int e = 1; e < NEXP; e++) mx = fmaxf(mx, acc[e]);
            float p[NEXP], se = 0.f;
#pragma unroll
            for (int e = 0; e < NEXP; e++) { p[e] = __expf(acc[e] - mx); se += p[e]; }
            float inv = 1.f / se;
            int i0 = 0;
#pragma unroll
            for (int e = 1; e < NEXP; e++) if (p[e] > p[i0]) i0 = e;
            int i1 = (i0 == 0) ? 1 : 0;
#pragma unroll
            for (int e = 0; e < NEXP; e++) if (e != i0 && p[e] > p[i1]) i1 = e;
            int p0 = atomicAdd(&lcnt[i0], 1);
            lt[i0][p0] = n; lw[i0][p0] = p[i0] * inv;
            int p1 = atomicAdd(&lcnt[i1], 1);
            lt[i1][p1] = n; lw[i1][p1] = p[i1] * inv;
        }
    }
    __syncthreads();
    if (tid < NEXP) base[tid] = atomicAdd(&cnt[tid * 16], lcnt[tid]);
    __syncthreads();
#pragma unroll
    for (int e = 0; e < NEXP; e++) {
        for (int i = tid; i < lcnt[e]; i += 256) {
            rows[e * NTOK + base[e] + i] = lt[e][i];
            wts [e * NTOK + base[e] + i] = lw[e][i];
        }
    }
}

// --------- scan: expert offsets + dense m-tile worklist ---------
__global__ void scan_offsets(const int* __restrict__ cnt, int* __restrict__ offs,
                             int* __restrict__ wl)
{
    if (threadIdx.x == 0) {
        int s = 0, t = 0;
        for (int e = 0; e < NEXP; e++) {
            int me = cnt[e * 16];
            offs[e] = s; s += me;
            for (int m0 = 0; m0 < me; m0 += BM) {
                wl[1 + 2 * t] = e; wl[2 + 2 * t] = m0; t++;
            }
        }
        wl[0] = t;
    }
}

// --------- x fp32 -> bf16 ---------
__global__ __launch_bounds__(256) void convert_x(
    const float* __restrict__ x, __hip_bfloat16* __restrict__ xb)
{
    size_t i = ((size_t)blockIdx.x * 256 + threadIdx.x) * 8;
    float4 v0 = *(const float4*)(x + i);
    float4 v1 = *(const float4*)(x + i + 4);
    Pack8 pk;
    pk.h[0] = __float2bfloat16(v0.x); pk.h[1] = __float2bfloat16(v0.y);
    pk.h[2] = __float2bfloat16(v0.z); pk.h[3] = __float2bfloat16(v0.w);
    pk.h[4] = __float2bfloat16(v1.x); pk.h[5] = __float2bfloat16(v1.y);
    pk.h[6] = __float2bfloat16(v1.z); pk.h[7] = __float2bfloat16(v1.w);
    *(short8*)(xb + i) = pk.v;
}

// ------------- transpose + fp32->bf16: src [E][R][C] -> dst [E][C][R] -------------
__global__ __launch_bounds__(256) void transpose_conv(
    const float* __restrict__ src, __hip_bfloat16* __restrict__ dst)
{
    __shared__ float t[32][33];
    const int e = blockIdx.z;
    const int r0 = blockIdx.x * 32, c0 = blockIdx.y * 32;
    const int tid = threadIdx.x;
    const int rr = tid >> 3;
    const int cc = (tid & 7) * 4;
    const float* p = src + ((size_t)e * 1024 + r0 + rr) * 1024 + c0 + cc;
    float4 v = *(const float4*)p;
    t[rr][cc] = v.x; t[rr][cc + 1] = v.y; t[rr][cc + 2] = v.z; t[rr][cc + 3] = v.w;
    __syncthreads();
    const int cr = tid >> 3;
    const int rc = (tid & 7) * 4;
    Pack4 o;
#pragma unroll
    for (int j = 0; j < 4; j++) o.h[j] = __float2bfloat16(t[rc + j][cr]);
    *(unsigned long long*)(dst + ((size_t)e * 1024 + c0 + cr) * 1024 + r0 + rc) = o.v;
}

// ---------------- GEMM1: hid = relu(Xb[rows] @ w1t^T), worklist grid ----------------
__global__ __launch_bounds__(256) void moe_gemm1(
    const __hip_bfloat16* __restrict__ xb, const __hip_bfloat16* __restrict__ w1t,
    const int* __restrict__ cnt, const int* __restrict__ offs,
    const int* __restrict__ wl, const int* __restrict__ rows,
    __hip_bfloat16* __restrict__ hid)
{
    const int t = blockIdx.y;
    if (t >= wl[0]) return;
    const int e = wl[1 + 2 * t], m0 = wl[2 + 2 * t];
    const int me = cnt[e * 16], off = offs[e];
    const int n0 = blockIdx.x * BN;
    const int tid = threadIdx.x;
    const int lane = tid & 63, wv = tid >> 6;
    const int wr = wv >> 1, wc = wv & 1;
    const int fr = lane & 15, fq = lane >> 4;

    __shared__ alignas(16) __hip_bfloat16 Al[BM][BK];
    __shared__ alignas(16) __hip_bfloat16 Bl[BN][BK];

    // staging: chunk c = i*256+tid covers row c>>3, cols (c&7)*8..+7
    const __hip_bfloat16* asrc[4];
    const __hip_bfloat16* bsrc[4];
#pragma unroll
    for (int i = 0; i < 4; i++) {
        int row = i * 32 + wv * 8 + (lane >> 3);
        int gi = m0 + row;
        int ri = gi < me ? gi : me - 1;
        int tok = rows[e * NTOK + ri];
        asrc[i] = xb + (size_t)tok * CDIM + (lane & 7) * 8;
        bsrc[i] = w1t + ((size_t)e * FDIM + n0 + row) * CDIM + (lane & 7) * 8;
    }

    f32x4 acc[4][4] = {};

    for (int k0 = 0; k0 < CDIM; k0 += BK) {
#pragma unroll
        for (int i = 0; i < 4; i++) {
            gload16(asrc[i] + k0, (__hip_bfloat16*)Al + (i * 256 + wv * 64) * 8);
            gload16(bsrc[i] + k0, (__hip_bfloat16*)Bl + (i * 256 + wv * 64) * 8);
        }
        __syncthreads();
#pragma unroll
        for (int ks = 0; ks < 2; ks++) {
            short8 af[4], bfv[4];
#pragma unroll
            for (int m = 0; m < 4; m++)
                af[m] = *(const short8*)&Al[wr * 64 + m * 16 + fr][ks * 32 + fq * 8];
#pragma unroll
            for (int n = 0; n < 4; n++)
                bfv[n] = *(const short8*)&Bl[wc * 64 + n * 16 + fr][ks * 32 + fq * 8];
#pragma unroll
            for (int m = 0; m < 4; m++)
#pragma unroll
                for (int n = 0; n < 4; n++)
                    acc[m][n] = __builtin_amdgcn_mfma_f32_16x16x32_bf16(
                        af[m], bfv[n], acc[m][n], 0, 0, 0);
        }
        __syncthreads();
    }

#pragma unroll
    for (int m = 0; m < 4; m++) {
#pragma unroll
        for (int n = 0; n < 4; n++) {
#pragma unroll
            for (int r = 0; r < 4; r++) {
                int il = wr * 64 + m * 16 + fq * 4 + r;
                int gi = m0 + il;
                if (gi < me) {
                    float v = acc[m][n][r];
                    v = v > 0.f ? v : 0.f;
                    hid[(size_t)(off + gi) * FDIM + n0 + wc * 64 + n * 16 + fr] =
                        __float2bfloat16(v);
                }
            }
        }
    }
}

// ---------------- GEMM2: out[tok] += wt * (hid @ w2t^T), worklist grid ----------------
__global__ __launch_bounds__(256) void moe_gemm2(
    const __hip_bfloat16* __restrict__ hid, const __hip_bfloat16* __restrict__ w2t,
    const int* __restrict__ cnt, const int* __restrict__ offs,
    const int* __restrict__ wl, const int* __restrict__ rows,
    const float* __restrict__ wts, float* __restrict__ out)
{
    const int t = blockIdx.y;
    if (t >= wl[0]) return;
    const int e = wl[1 + 2 * t], m0 = wl[2 + 2 * t];
    const int me = cnt[e * 16], off = offs[e];
    const int n0 = blockIdx.x * BN;
    const int tid = threadIdx.x;
    const int lane = tid & 63, wv = tid >> 6;
    const int wr = wv >> 1, wc = wv & 1;
    const int fr = lane & 15, fq = lane >> 4;

    __shared__ alignas(16) __hip_bfloat16 Al[BM][BK];
    __shared__ alignas(16) __hip_bfloat16 Bl[BN][BK];
    __shared__ int rtok[BM];
    __shared__ float rwt[BM];

    if (tid < BM) {
        int gi = m0 + tid;
        int ri = gi < me ? gi : me - 1;
        rtok[tid] = rows[e * NTOK + ri];
        rwt[tid] = gi < me ? wts[e * NTOK + ri] : 0.f;
    }

    const __hip_bfloat16* asrc[4];
    const __hip_bfloat16* bsrc[4];
#pragma unroll
    for (int i = 0; i < 4; i++) {
        int row = i * 32 + wv * 8 + (lane >> 3);
        int gi = m0 + row;
        int ri = gi < me ? gi : me - 1;
        asrc[i] = hid + (size_t)(off + ri) * FDIM + (lane & 7) * 8;
        bsrc[i] = w2t + ((size_t)e * CDIM + n0 + row) * FDIM + (lane & 7) * 8;
    }

    f32x4 acc[4][4] = {};

    for (int k0 = 0; k0 < FDIM; k0 += BK) {
#pragma unroll
        for (int i = 0; i < 4; i++) {
            gload16(asrc[i] + k0, (__hip_bfloat16*)Al + (i * 256 + wv * 64) * 8);
            gload16(bsrc[i] + k0, (__hip_bfloat16*)Bl + (i * 256 + wv * 64) * 8);
        }
        __syncthreads();
#pragma unroll
        for (int ks = 0; ks < 2; ks++) {
            short8 af[4], bfv[4];
#pragma unroll
            for (int m = 0; m < 4; m++)
                af[m] = *(const short8*)&Al[wr * 64 + m * 16 + fr][ks * 32 + fq * 8];
#pragma unroll
            for (int n = 0; n < 4; n++)
                bfv[n] = *(const short8*)&Bl[wc * 64 + n * 16 + fr][ks * 32 + fq * 8];
#pragma unroll
            for (int m = 0; m < 4; m++)
#pragma unroll
                for (int n = 0; n < 4; n++)
                    acc[m][n] = __builtin_amdgcn_mfma_f32_16x16x32_bf16(
                        af[m], bfv[n], acc[m][n], 0, 0, 0);
        }
        __syncthreads();
    }

#pragma unroll
    for (int m = 0; m < 4; m++) {
#pragma unroll
        for (int n = 0; n < 4; n++) {
#pragma unroll
            for (int r = 0; r < 4; r++) {
                int il = wr * 64 + m * 16 + fq * 4 + r;
                int gi = m0 + il;
                if (gi < me) {
                    atomicAdd(&out[(size_t)rtok[il] * CDIM + n0 + wc * 64 + n * 16 + fr],
                              rwt[il] * acc[m][n][r]);
                }
            }
        }
    }
}

// ---------------- launch ----------------
extern "C" void kernel_launch(void* const* d_in, const int* in_sizes, int n_in,
                              void* d_out, int out_size, void* d_ws, size_t ws_size,
                              hipStream_t stream)
{
    const float* x  = (const float*)d_in[0];
    const float* rw = (const float*)d_in[1];
    const float* w1 = (const float*)d_in[2];
    const float* w2 = (const float*)d_in[3];
    float* out = (float*)d_out;
    char* ws = (char*)d_ws;

    int* cnt  = (int*)ws;                          // 8 counters, 64B stride
    int* offs = (int*)(ws + 1024);
    int* wl   = (int*)(ws + 2048);                 // worklist: count + (e,m0) pairs
    int* rows = (int*)(ws + 4096);                 // [E][NTOK]
    float* wts = (float*)(ws + 4096 + NEXP * NTOK * 4);
    __hip_bfloat16* xb  = (__hip_bfloat16*)(ws + (1u << 20));            // 16 MB
    __hip_bfloat16* w1t = (__hip_bfloat16*)(ws + (17u << 20));           // 16 MB
    __hip_bfloat16* hid = (__hip_bfloat16*)(ws + (33u << 20));           // 32 MB
    __hip_bfloat16* w2t = xb;  // xb dead after gemm1; w2 transposed after gemm1

    hipMemsetAsync(cnt, 0, 1024, stream);
    hipMemsetAsync(d_out, 0, (size_t)out_size * sizeof(float), stream);

    router_kernel<<<NTOK / 16, 256, 0, stream>>>(x, rw, cnt, rows, wts);
    scan_offsets<<<1, 64, 0, stream>>>(cnt, offs, wl);
    convert_x<<<NTOK * CDIM / 2048, 256, 0, stream>>>(x, xb);
    transpose_conv<<<dim3(32, 32, NEXP), 256, 0, stream>>>(w1, w1t);
    moe_gemm1<<<dim3(FDIM / BN, MAXT), 256, 0, stream>>>(
        xb, w1t, cnt, offs, wl, rows, hid);
    transpose_conv<<<dim3(32, 32, NEXP), 256, 0, stream>>>(w2, w2t);
    moe_gemm2<<<dim3(CDIM / BN, MAXT), 256, 0, stream>>>(
        hid, w2t, cnt, offs, wl, rows, wts, out);
}

// Round 4
// 217.400 us; speedup vs baseline: 2.3264x; 1.1643x over previous
//
#include <hip/hip_runtime.h>
#include <hip/hip_bf16.h>

#define NTOK 8192
#define CDIM 1024
#define FDIM 1024
#define NEXP 8
#define BM 128
#define BN 128
#define BK 64
#define MAXT 136          // sum ceil(me/BM) <= 2*NTOK/BM + NEXP
#define NWG (8 * MAXT)    // 1088 = 8 XCD chunks x 136

typedef __attribute__((ext_vector_type(8))) short short8;
typedef __attribute__((ext_vector_type(4))) float f32x4;

union Pack8 { __hip_bfloat16 h[8]; short8 v; };
union Pack4 { __hip_bfloat16 h[4]; unsigned long long v; };
union U4 { unsigned long long u; unsigned short s[4]; };

typedef const unsigned int __attribute__((address_space(1)))* gas_ptr;
typedef unsigned int __attribute__((address_space(3)))* las_ptr;

__device__ __forceinline__ void gload16(const void* g, void* l) {
    __builtin_amdgcn_global_load_lds(
        (gas_ptr)(unsigned long long)g,
        (las_ptr)(unsigned int)(unsigned long long)l,
        16, 0, 0);
}

__device__ __forceinline__ float bf2f(unsigned short v) {
    unsigned int t = (unsigned int)v << 16;
    return __uint_as_float(t);
}

// ------- router: fused x->bf16 convert + logits + top-2 scatter (rank in bit16) -------
__global__ __launch_bounds__(256) void router_kernel(
    const float* __restrict__ x, const float* __restrict__ rw,
    __hip_bfloat16* __restrict__ xb,
    int* __restrict__ cnt, int* __restrict__ rows, float* __restrict__ wts)
{
    __shared__ int lcnt[NEXP];
    __shared__ int lt[NEXP][32];
    __shared__ float lw[NEXP][32];
    __shared__ int base[NEXP];
    const int tid = threadIdx.x;
    const int wv = tid >> 6, lane = tid & 63;
    if (tid < NEXP) lcnt[tid] = 0;
    __syncthreads();

    for (int tt = 0; tt < 4; tt++) {
        const int n = blockIdx.x * 16 + wv * 4 + tt;
        float acc[NEXP];
#pragma unroll
        for (int e = 0; e < NEXP; e++) acc[e] = 0.f;
#pragma unroll
        for (int c0 = 0; c0 < CDIM; c0 += 256) {
            const size_t o = (size_t)n * CDIM + c0 + lane * 4;
            float4 xv = *(const float4*)(x + o);
            Pack4 p4;
            p4.h[0] = __float2bfloat16(xv.x); p4.h[1] = __float2bfloat16(xv.y);
            p4.h[2] = __float2bfloat16(xv.z); p4.h[3] = __float2bfloat16(xv.w);
            *(unsigned long long*)(xb + o) = p4.v;
#pragma unroll
            for (int e = 0; e < NEXP; e++) {
                float4 w4 = *(const float4*)&rw[e * CDIM + c0 + lane * 4];
                acc[e] += xv.x * w4.x + xv.y * w4.y + xv.z * w4.z + xv.w * w4.w;
            }
        }
#pragma unroll
        for (int e = 0; e < NEXP; e++) {
#pragma unroll
            for (int s = 32; s > 0; s >>= 1) acc[e] += __shfl_xor(acc[e], s);
        }
        if (lane == 0) {
            float mx = acc[0];
#pragma unroll
            for (int e = 1; e < NEXP; e++) mx = fmaxf(mx, acc[e]);
            float p[NEXP], se = 0.f;
#pragma unroll
            for (int e = 0; e < NEXP; e++) { p[e] = __expf(acc[e] - mx); se += p[e]; }
            float inv = 1.f / se;
            int i0 = 0;
#pragma unroll
            for (int e = 1; e < NEXP; e++) if (p[e] > p[i0]) i0 = e;
            int i1 = (i0 == 0) ? 1 : 0;
#pragma unroll
            for (int e = 0; e < NEXP; e++) if (e != i0 && p[e] > p[i1]) i1 = e;
            int p0 = atomicAdd(&lcnt[i0], 1);
            lt[i0][p0] = n;                 // rank 0
            lw[i0][p0] = p[i0] * inv;
            int p1 = atomicAdd(&lcnt[i1], 1);
            lt[i1][p1] = n | (1 << 16);     // rank 1
            lw[i1][p1] = p[i1] * inv;
        }
    }
    __syncthreads();
    if (tid < NEXP) base[tid] = atomicAdd(&cnt[tid * 16], lcnt[tid]);
    __syncthreads();
#pragma unroll
    for (int e = 0; e < NEXP; e++) {
        for (int i = tid; i < lcnt[e]; i += 256) {
            rows[e * NTOK + base[e] + i] = lt[e][i];
            wts [e * NTOK + base[e] + i] = lw[e][i];
        }
    }
}

// --------- scan: expert offsets + dense m-tile worklist ---------
__global__ void scan_offsets(const int* __restrict__ cnt, int* __restrict__ offs,
                             int* __restrict__ wl)
{
    if (threadIdx.x == 0) {
        int s = 0, t = 0;
        for (int e = 0; e < NEXP; e++) {
            int me = cnt[e * 16];
            offs[e] = s; s += me;
            for (int m0 = 0; m0 < me; m0 += BM) {
                wl[1 + 2 * t] = e; wl[2 + 2 * t] = m0; t++;
            }
        }
        wl[0] = t;
    }
}

// --------- invert: slot[2n + rank] = off[e] + i ---------
__global__ __launch_bounds__(256) void build_slots(
    const int* __restrict__ cnt, const int* __restrict__ offs,
    const int* __restrict__ rows, int* __restrict__ slot)
{
    const int e = blockIdx.y;
    const int i = blockIdx.x * 256 + threadIdx.x;
    if (i < cnt[e * 16]) {
        int p = rows[e * NTOK + i];
        slot[2 * (p & 0xFFFF) + (p >> 16)] = offs[e] + i;
    }
}

// ------------- transpose + fp32->bf16: src [E][R][C] -> dst [E][C][R] -------------
__global__ __launch_bounds__(256) void transpose_conv(
    const float* __restrict__ src, __hip_bfloat16* __restrict__ dst)
{
    __shared__ float t[32][33];
    const int e = blockIdx.z;
    const int r0 = blockIdx.x * 32, c0 = blockIdx.y * 32;
    const int tid = threadIdx.x;
    const int rr = tid >> 3;
    const int cc = (tid & 7) * 4;
    const float* p = src + ((size_t)e * 1024 + r0 + rr) * 1024 + c0 + cc;
    float4 v = *(const float4*)p;
    t[rr][cc] = v.x; t[rr][cc + 1] = v.y; t[rr][cc + 2] = v.z; t[rr][cc + 3] = v.w;
    __syncthreads();
    const int cr = tid >> 3;
    const int rc = (tid & 7) * 4;
    Pack4 o;
#pragma unroll
    for (int j = 0; j < 4; j++) o.h[j] = __float2bfloat16(t[rc + j][cr]);
    *(unsigned long long*)(dst + ((size_t)e * 1024 + c0 + cr) * 1024 + r0 + rc) = o.v;
}

// ---------------- GEMM1: hid = relu(Xb[rows] @ w1t^T) ----------------
__global__ __launch_bounds__(256, 4) void moe_gemm1(
    const __hip_bfloat16* __restrict__ xb, const __hip_bfloat16* __restrict__ w1t,
    const int* __restrict__ cnt, const int* __restrict__ offs,
    const int* __restrict__ wl, const int* __restrict__ rows,
    __hip_bfloat16* __restrict__ hid)
{
    const int bid = blockIdx.x;
    const int wid = (bid & 7) * MAXT + (bid >> 3);   // XCD-chunked
    const int t = wid >> 3;
    if (t >= wl[0]) return;
    const int n0 = (wid & 7) * BN;
    const int e = wl[1 + 2 * t], m0 = wl[2 + 2 * t];
    const int me = cnt[e * 16], off = offs[e];
    const int tid = threadIdx.x;
    const int lane = tid & 63, wv = tid >> 6;
    const int wr = wv >> 1, wc = wv & 1;
    const int fr = lane & 15, fq = lane >> 4;

    __shared__ alignas(16) __hip_bfloat16 Al[BM][BK];
    __shared__ alignas(16) __hip_bfloat16 Bl[BN][BK];

    const __hip_bfloat16* asrc[4];
    const __hip_bfloat16* bsrc[4];
#pragma unroll
    for (int i = 0; i < 4; i++) {
        int row = i * 32 + wv * 8 + (lane >> 3);
        int gi = m0 + row;
        int ri = gi < me ? gi : me - 1;
        int tok = rows[e * NTOK + ri] & 0xFFFF;
        asrc[i] = xb + (size_t)tok * CDIM + (lane & 7) * 8;
        bsrc[i] = w1t + ((size_t)e * FDIM + n0 + row) * CDIM + (lane & 7) * 8;
    }

    f32x4 acc[4][4] = {};

    for (int k0 = 0; k0 < CDIM; k0 += BK) {
#pragma unroll
        for (int i = 0; i < 4; i++) {
            gload16(asrc[i] + k0, (__hip_bfloat16*)Al + (i * 256 + wv * 64) * 8);
            gload16(bsrc[i] + k0, (__hip_bfloat16*)Bl + (i * 256 + wv * 64) * 8);
        }
        __syncthreads();
#pragma unroll
        for (int ks = 0; ks < 2; ks++) {
            short8 af[4], bfv[4];
#pragma unroll
            for (int m = 0; m < 4; m++)
                af[m] = *(const short8*)&Al[wr * 64 + m * 16 + fr][ks * 32 + fq * 8];
#pragma unroll
            for (int n = 0; n < 4; n++)
                bfv[n] = *(const short8*)&Bl[wc * 64 + n * 16 + fr][ks * 32 + fq * 8];
#pragma unroll
            for (int m = 0; m < 4; m++)
#pragma unroll
                for (int n = 0; n < 4; n++)
                    acc[m][n] = __builtin_amdgcn_mfma_f32_16x16x32_bf16(
                        af[m], bfv[n], acc[m][n], 0, 0, 0);
        }
        __syncthreads();
    }

#pragma unroll
    for (int m = 0; m < 4; m++) {
#pragma unroll
        for (int n = 0; n < 4; n++) {
#pragma unroll
            for (int r = 0; r < 4; r++) {
                int il = wr * 64 + m * 16 + fq * 4 + r;
                int gi = m0 + il;
                if (gi < me) {
                    float v = acc[m][n][r];
                    v = v > 0.f ? v : 0.f;
                    hid[(size_t)(off + gi) * FDIM + n0 + wc * 64 + n * 16 + fr] =
                        __float2bfloat16(v);
                }
            }
        }
    }
}

// ------- GEMM2: ybuf[slot] = wt * (hid @ w2t^T)  (or atomic fallback) -------
__global__ __launch_bounds__(256, 4) void moe_gemm2(
    const __hip_bfloat16* __restrict__ hid, const __hip_bfloat16* __restrict__ w2t,
    const int* __restrict__ cnt, const int* __restrict__ offs,
    const int* __restrict__ wl, const int* __restrict__ rows,
    const float* __restrict__ wts, __hip_bfloat16* __restrict__ ybuf,
    float* __restrict__ out)
{
    const int bid = blockIdx.x;
    const int wid = (bid & 7) * MAXT + (bid >> 3);
    const int t = wid >> 3;
    if (t >= wl[0]) return;
    const int n0 = (wid & 7) * BN;
    const int e = wl[1 + 2 * t], m0 = wl[2 + 2 * t];
    const int me = cnt[e * 16], off = offs[e];
    const int tid = threadIdx.x;
    const int lane = tid & 63, wv = tid >> 6;
    const int wr = wv >> 1, wc = wv & 1;
    const int fr = lane & 15, fq = lane >> 4;

    __shared__ alignas(16) __hip_bfloat16 Al[BM][BK];
    __shared__ alignas(16) __hip_bfloat16 Bl[BN][BK];
    __shared__ int rtok[BM];
    __shared__ float rwt[BM];

    if (tid < BM) {
        int gi = m0 + tid;
        int ri = gi < me ? gi : me - 1;
        rtok[tid] = rows[e * NTOK + ri] & 0xFFFF;
        rwt[tid] = gi < me ? wts[e * NTOK + ri] : 0.f;
    }

    const __hip_bfloat16* asrc[4];
    const __hip_bfloat16* bsrc[4];
#pragma unroll
    for (int i = 0; i < 4; i++) {
        int row = i * 32 + wv * 8 + (lane >> 3);
        int gi = m0 + row;
        int ri = gi < me ? gi : me - 1;
        asrc[i] = hid + (size_t)(off + ri) * FDIM + (lane & 7) * 8;
        bsrc[i] = w2t + ((size_t)e * CDIM + n0 + row) * FDIM + (lane & 7) * 8;
    }

    f32x4 acc[4][4] = {};

    for (int k0 = 0; k0 < FDIM; k0 += BK) {
#pragma unroll
        for (int i = 0; i < 4; i++) {
            gload16(asrc[i] + k0, (__hip_bfloat16*)Al + (i * 256 + wv * 64) * 8);
            gload16(bsrc[i] + k0, (__hip_bfloat16*)Bl + (i * 256 + wv * 64) * 8);
        }
        __syncthreads();
#pragma unroll
        for (int ks = 0; ks < 2; ks++) {
            short8 af[4], bfv[4];
#pragma unroll
            for (int m = 0; m < 4; m++)
                af[m] = *(const short8*)&Al[wr * 64 + m * 16 + fr][ks * 32 + fq * 8];
#pragma unroll
            for (int n = 0; n < 4; n++)
                bfv[n] = *(const short8*)&Bl[wc * 64 + n * 16 + fr][ks * 32 + fq * 8];
#pragma unroll
            for (int m = 0; m < 4; m++)
#pragma unroll
                for (int n = 0; n < 4; n++)
                    acc[m][n] = __builtin_amdgcn_mfma_f32_16x16x32_bf16(
                        af[m], bfv[n], acc[m][n], 0, 0, 0);
        }
        __syncthreads();
    }

    if (ybuf) {
#pragma unroll
        for (int m = 0; m < 4; m++) {
#pragma unroll
            for (int n = 0; n < 4; n++) {
#pragma unroll
                for (int r = 0; r < 4; r++) {
                    int il = wr * 64 + m * 16 + fq * 4 + r;
                    int gi = m0 + il;
                    if (gi < me)
                        ybuf[(size_t)(off + gi) * CDIM + n0 + wc * 64 + n * 16 + fr] =
                            __float2bfloat16(rwt[il] * acc[m][n][r]);
                }
            }
        }
    } else {
#pragma unroll
        for (int m = 0; m < 4; m++) {
#pragma unroll
            for (int n = 0; n < 4; n++) {
#pragma unroll
                for (int r = 0; r < 4; r++) {
                    int il = wr * 64 + m * 16 + fq * 4 + r;
                    int gi = m0 + il;
                    if (gi < me)
                        atomicAdd(&out[(size_t)rtok[il] * CDIM + n0 + wc * 64 + n * 16 + fr],
                                  rwt[il] * acc[m][n][r]);
                }
            }
        }
    }
}

// ---------------- gather: out[n] = y[slot0] + y[slot1] ----------------
__global__ __launch_bounds__(256) void gather_out(
    const __hip_bfloat16* __restrict__ yb, const int* __restrict__ slot,
    float* __restrict__ out)
{
    for (int n = blockIdx.x; n < NTOK; n += gridDim.x) {
        const int s0 = slot[2 * n], s1 = slot[2 * n + 1];
        const int c = threadIdx.x * 4;
        U4 a, b;
        a.u = *(const unsigned long long*)(yb + (size_t)s0 * CDIM + c);
        b.u = *(const unsigned long long*)(yb + (size_t)s1 * CDIM + c);
        float4 o;
        o.x = bf2f(a.s[0]) + bf2f(b.s[0]);
        o.y = bf2f(a.s[1]) + bf2f(b.s[1]);
        o.z = bf2f(a.s[2]) + bf2f(b.s[2]);
        o.w = bf2f(a.s[3]) + bf2f(b.s[3]);
        *(float4*)(out + (size_t)n * CDIM + c) = o;
    }
}

// ---------------- launch ----------------
extern "C" void kernel_launch(void* const* d_in, const int* in_sizes, int n_in,
                              void* d_out, int out_size, void* d_ws, size_t ws_size,
                              hipStream_t stream)
{
    const float* x  = (const float*)d_in[0];
    const float* rw = (const float*)d_in[1];
    const float* w1 = (const float*)d_in[2];
    const float* w2 = (const float*)d_in[3];
    float* out = (float*)d_out;
    char* ws = (char*)d_ws;

    int* cnt  = (int*)ws;                             // 8 counters, 64B stride
    int* offs = (int*)(ws + 1024);
    int* wl   = (int*)(ws + 2048);
    int* rows = (int*)(ws + 4096);                    // [E][NTOK]
    float* wts = (float*)(ws + 4096 + NEXP * NTOK * 4);
    int* slot = (int*)(ws + 4096 + 2 * NEXP * NTOK * 4);  // [NTOK][2]
    __hip_bfloat16* xb  = (__hip_bfloat16*)(ws + (1u << 20));    // 16 MB
    __hip_bfloat16* w1t = (__hip_bfloat16*)(ws + (17u << 20));   // 16 MB
    __hip_bfloat16* hid = (__hip_bfloat16*)(ws + (33u << 20));   // 32 MB
    __hip_bfloat16* w2t = w1t;  // w1t dead after gemm1
    const bool big = ws_size >= ((size_t)98 << 20);
    __hip_bfloat16* ybuf = big ? (__hip_bfloat16*)(ws + (65u << 20)) : nullptr; // 32 MB

    hipMemsetAsync(cnt, 0, 1024, stream);
    if (!big)
        hipMemsetAsync(d_out, 0, (size_t)out_size * sizeof(float), stream);

    router_kernel<<<NTOK / 16, 256, 0, stream>>>(x, rw, xb, cnt, rows, wts);
    scan_offsets<<<1, 64, 0, stream>>>(cnt, offs, wl);
    build_slots<<<dim3(NTOK / 256, NEXP), 256, 0, stream>>>(cnt, offs, rows, slot);
    transpose_conv<<<dim3(32, 32, NEXP), 256, 0, stream>>>(w1, w1t);
    moe_gemm1<<<NWG, 256, 0, stream>>>(xb, w1t, cnt, offs, wl, rows, hid);
    transpose_conv<<<dim3(32, 32, NEXP), 256, 0, stream>>>(w2, w2t);
    moe_gemm2<<<NWG, 256, 0, stream>>>(hid, w2t, cnt, offs, wl, rows, wts, ybuf, out);
    if (big)
        gather_out<<<2048, 256, 0, stream>>>(ybuf, slot, out);
}

// Round 5
// 188.270 us; speedup vs baseline: 2.6864x; 1.1547x over previous
//
#include <hip/hip_runtime.h>
#include <hip/hip_bf16.h>

#define NTOK 8192
#define CDIM 1024
#define FDIM 1024
#define NEXP 8
#define BM 128
#define BN 128
#define BK 64
#define NKT (CDIM / BK)   // 16 K-steps
#define MAXT 136          // sum ceil(me/BM) <= 2*NTOK/BM + NEXP
#define NWG (8 * MAXT)    // 1088 = 8 XCD chunks x 136

typedef __attribute__((ext_vector_type(8))) short short8;
typedef __attribute__((ext_vector_type(4))) float f32x4;

union Pack8 { __hip_bfloat16 h[8]; short8 v; };
union Pack4 { __hip_bfloat16 h[4]; unsigned long long v; };
union U4 { unsigned long long u; unsigned short s[4]; };

typedef const unsigned int __attribute__((address_space(1)))* gas_ptr;
typedef unsigned int __attribute__((address_space(3)))* las_ptr;

__device__ __forceinline__ void gload16(const void* g, void* l) {
    __builtin_amdgcn_global_load_lds(
        (gas_ptr)(unsigned long long)g,
        (las_ptr)(unsigned int)(unsigned long long)l,
        16, 0, 0);
}

__device__ __forceinline__ float bf2f(unsigned short v) {
    unsigned int t = (unsigned int)v << 16;
    return __uint_as_float(t);
}

// ------- router: fused x->bf16 convert + logits + top-2 scatter (rank in bit16) -------
__global__ __launch_bounds__(256) void router_kernel(
    const float* __restrict__ x, const float* __restrict__ rw,
    __hip_bfloat16* __restrict__ xb,
    int* __restrict__ cnt, int* __restrict__ rows, float* __restrict__ wts)
{
    __shared__ int lcnt[NEXP];
    __shared__ int lt[NEXP][32];
    __shared__ float lw[NEXP][32];
    __shared__ int base[NEXP];
    const int tid = threadIdx.x;
    const int wv = tid >> 6, lane = tid & 63;
    if (tid < NEXP) lcnt[tid] = 0;
    __syncthreads();

    for (int tt = 0; tt < 4; tt++) {
        const int n = blockIdx.x * 16 + wv * 4 + tt;
        float acc[NEXP];
#pragma unroll
        for (int e = 0; e < NEXP; e++) acc[e] = 0.f;
#pragma unroll
        for (int c0 = 0; c0 < CDIM; c0 += 256) {
            const size_t o = (size_t)n * CDIM + c0 + lane * 4;
            float4 xv = *(const float4*)(x + o);
            Pack4 p4;
            p4.h[0] = __float2bfloat16(xv.x); p4.h[1] = __float2bfloat16(xv.y);
            p4.h[2] = __float2bfloat16(xv.z); p4.h[3] = __float2bfloat16(xv.w);
            *(unsigned long long*)(xb + o) = p4.v;
#pragma unroll
            for (int e = 0; e < NEXP; e++) {
                float4 w4 = *(const float4*)&rw[e * CDIM + c0 + lane * 4];
                acc[e] += xv.x * w4.x + xv.y * w4.y + xv.z * w4.z + xv.w * w4.w;
            }
        }
#pragma unroll
        for (int e = 0; e < NEXP; e++) {
#pragma unroll
            for (int s = 32; s > 0; s >>= 1) acc[e] += __shfl_xor(acc[e], s);
        }
        if (lane == 0) {
            float mx = acc[0];
#pragma unroll
            for (int e = 1; e < NEXP; e++) mx = fmaxf(mx, acc[e]);
            float p[NEXP], se = 0.f;
#pragma unroll
            for (int e = 0; e < NEXP; e++) { p[e] = __expf(acc[e] - mx); se += p[e]; }
            float inv = 1.f / se;
            int i0 = 0;
#pragma unroll
            for (int e = 1; e < NEXP; e++) if (p[e] > p[i0]) i0 = e;
            int i1 = (i0 == 0) ? 1 : 0;
#pragma unroll
            for (int e = 0; e < NEXP; e++) if (e != i0 && p[e] > p[i1]) i1 = e;
            int p0 = atomicAdd(&lcnt[i0], 1);
            lt[i0][p0] = n;
            lw[i0][p0] = p[i0] * inv;
            int p1 = atomicAdd(&lcnt[i1], 1);
            lt[i1][p1] = n | (1 << 16);
            lw[i1][p1] = p[i1] * inv;
        }
    }
    __syncthreads();
    if (tid < NEXP) base[tid] = atomicAdd(&cnt[tid * 16], lcnt[tid]);
    __syncthreads();
#pragma unroll
    for (int e = 0; e < NEXP; e++) {
        for (int i = tid; i < lcnt[e]; i += 256) {
            rows[e * NTOK + base[e] + i] = lt[e][i];
            wts [e * NTOK + base[e] + i] = lw[e][i];
        }
    }
}

// --------- scan: expert offsets + dense m-tile worklist ---------
__global__ void scan_offsets(const int* __restrict__ cnt, int* __restrict__ offs,
                             int* __restrict__ wl)
{
    if (threadIdx.x == 0) {
        int s = 0, t = 0;
        for (int e = 0; e < NEXP; e++) {
            int me = cnt[e * 16];
            offs[e] = s; s += me;
            for (int m0 = 0; m0 < me; m0 += BM) {
                wl[1 + 2 * t] = e; wl[2 + 2 * t] = m0; t++;
            }
        }
        wl[0] = t;
    }
}

// --------- invert: slot[2n + rank] = off[e] + i ---------
__global__ __launch_bounds__(256) void build_slots(
    const int* __restrict__ cnt, const int* __restrict__ offs,
    const int* __restrict__ rows, int* __restrict__ slot)
{
    const int e = blockIdx.y;
    const int i = blockIdx.x * 256 + threadIdx.x;
    if (i < cnt[e * 16]) {
        int p = rows[e * NTOK + i];
        slot[2 * (p & 0xFFFF) + (p >> 16)] = offs[e] + i;
    }
}

// ------------- transpose + fp32->bf16: src [E][R][C] -> dst [E][C][R] -------------
__global__ __launch_bounds__(256) void transpose_conv(
    const float* __restrict__ src, __hip_bfloat16* __restrict__ dst)
{
    __shared__ float t[32][33];
    const int e = blockIdx.z;
    const int r0 = blockIdx.x * 32, c0 = blockIdx.y * 32;
    const int tid = threadIdx.x;
    const int rr = tid >> 3;
    const int cc = (tid & 7) * 4;
    const float* p = src + ((size_t)e * 1024 + r0 + rr) * 1024 + c0 + cc;
    float4 v = *(const float4*)p;
    t[rr][cc] = v.x; t[rr][cc + 1] = v.y; t[rr][cc + 2] = v.z; t[rr][cc + 3] = v.w;
    __syncthreads();
    const int cr = tid >> 3;
    const int rc = (tid & 7) * 4;
    Pack4 o;
#pragma unroll
    for (int j = 0; j < 4; j++) o.h[j] = __float2bfloat16(t[rc + j][cr]);
    *(unsigned long long*)(dst + ((size_t)e * 1024 + c0 + cr) * 1024 + r0 + rc) = o.v;
}

// ---------------- GEMM1: hid = relu(Xb[rows] @ w1t^T), double-buffered ----------------
__global__ __launch_bounds__(256, 2) void moe_gemm1(
    const __hip_bfloat16* __restrict__ xb, const __hip_bfloat16* __restrict__ w1t,
    const int* __restrict__ cnt, const int* __restrict__ offs,
    const int* __restrict__ wl, const int* __restrict__ rows,
    __hip_bfloat16* __restrict__ hid)
{
    const int bid = blockIdx.x;
    const int wid = (bid & 7) * MAXT + (bid >> 3);   // XCD-chunked
    const int t = wid >> 3;
    if (t >= wl[0]) return;
    const int n0 = (wid & 7) * BN;
    const int e = wl[1 + 2 * t], m0 = wl[2 + 2 * t];
    const int me = cnt[e * 16], off = offs[e];
    const int tid = threadIdx.x;
    const int lane = tid & 63, wv = tid >> 6;
    const int wr = wv >> 1, wc = wv & 1;
    const int fr = lane & 15, fq = lane >> 4;

    // [dbuf][A=0/B=1][BM*BK] bf16 = 64 KB
    __shared__ alignas(16) __hip_bfloat16 smem[2][2][BM * BK];

    const __hip_bfloat16* asrc[4];
    const __hip_bfloat16* bsrc[4];
#pragma unroll
    for (int i = 0; i < 4; i++) {
        int row = i * 32 + wv * 8 + (lane >> 3);
        int gi = m0 + row;
        int ri = gi < me ? gi : me - 1;
        int tok = rows[e * NTOK + ri] & 0xFFFF;
        asrc[i] = xb + (size_t)tok * CDIM + (lane & 7) * 8;
        bsrc[i] = w1t + ((size_t)e * FDIM + n0 + row) * CDIM + (lane & 7) * 8;
    }

    f32x4 acc[4][4] = {};

    // prologue: stage k0=0 into buf 0
#pragma unroll
    for (int i = 0; i < 4; i++) {
        gload16(asrc[i], &smem[0][0][(i * 256 + wv * 64) * 8]);
        gload16(bsrc[i], &smem[0][1][(i * 256 + wv * 64) * 8]);
    }
    __syncthreads();

    int cur = 0;
    for (int kt = 0; kt < NKT; kt++) {
        if (kt + 1 < NKT) {
            const int k1 = (kt + 1) * BK;
#pragma unroll
            for (int i = 0; i < 4; i++) {
                gload16(asrc[i] + k1, &smem[cur ^ 1][0][(i * 256 + wv * 64) * 8]);
                gload16(bsrc[i] + k1, &smem[cur ^ 1][1][(i * 256 + wv * 64) * 8]);
            }
        }
#pragma unroll
        for (int ks = 0; ks < 2; ks++) {
            short8 af[4], bfv[4];
#pragma unroll
            for (int m = 0; m < 4; m++)
                af[m] = *(const short8*)&smem[cur][0][(wr * 64 + m * 16 + fr) * BK + ks * 32 + fq * 8];
#pragma unroll
            for (int n = 0; n < 4; n++)
                bfv[n] = *(const short8*)&smem[cur][1][(wc * 64 + n * 16 + fr) * BK + ks * 32 + fq * 8];
#pragma unroll
            for (int m = 0; m < 4; m++)
#pragma unroll
                for (int n = 0; n < 4; n++)
                    acc[m][n] = __builtin_amdgcn_mfma_f32_16x16x32_bf16(
                        af[m], bfv[n], acc[m][n], 0, 0, 0);
        }
        __syncthreads();   // drains vmcnt (next-buf stage complete) + protects reuse
        cur ^= 1;
    }

    // epilogue: stage C through LDS for full-line coalesced stores
    __hip_bfloat16 (*Cl)[BN] = reinterpret_cast<__hip_bfloat16(*)[BN]>(&smem[0][0][0]);
#pragma unroll
    for (int m = 0; m < 4; m++)
#pragma unroll
        for (int n = 0; n < 4; n++)
#pragma unroll
            for (int r = 0; r < 4; r++) {
                int il = wr * 64 + m * 16 + fq * 4 + r;
                float v = acc[m][n][r];
                Cl[il][wc * 64 + n * 16 + fr] = __float2bfloat16(v > 0.f ? v : 0.f);
            }
    __syncthreads();
#pragma unroll
    for (int i = 0; i < 8; i++) {
        int chunk = i * 256 + tid;
        int row = chunk >> 4, c8 = (chunk & 15) * 8;
        int gi = m0 + row;
        if (gi < me)
            *(short8*)(hid + (size_t)(off + gi) * FDIM + n0 + c8) =
                *(const short8*)&Cl[row][c8];
    }
}

// ------- GEMM2: ybuf[slot] = wt * (hid @ w2t^T), double-buffered -------
__global__ __launch_bounds__(256, 2) void moe_gemm2(
    const __hip_bfloat16* __restrict__ hid, const __hip_bfloat16* __restrict__ w2t,
    const int* __restrict__ cnt, const int* __restrict__ offs,
    const int* __restrict__ wl, const int* __restrict__ rows,
    const float* __restrict__ wts, __hip_bfloat16* __restrict__ ybuf,
    float* __restrict__ out)
{
    const int bid = blockIdx.x;
    const int wid = (bid & 7) * MAXT + (bid >> 3);
    const int t = wid >> 3;
    if (t >= wl[0]) return;
    const int n0 = (wid & 7) * BN;
    const int e = wl[1 + 2 * t], m0 = wl[2 + 2 * t];
    const int me = cnt[e * 16], off = offs[e];
    const int tid = threadIdx.x;
    const int lane = tid & 63, wv = tid >> 6;
    const int wr = wv >> 1, wc = wv & 1;
    const int fr = lane & 15, fq = lane >> 4;

    __shared__ alignas(16) __hip_bfloat16 smem[2][2][BM * BK];
    __shared__ int rtok[BM];
    __shared__ float rwt[BM];

    if (tid < BM) {
        int gi = m0 + tid;
        int ri = gi < me ? gi : me - 1;
        rtok[tid] = rows[e * NTOK + ri] & 0xFFFF;
        rwt[tid] = gi < me ? wts[e * NTOK + ri] : 0.f;
    }

    const __hip_bfloat16* asrc[4];
    const __hip_bfloat16* bsrc[4];
#pragma unroll
    for (int i = 0; i < 4; i++) {
        int row = i * 32 + wv * 8 + (lane >> 3);
        int gi = m0 + row;
        int ri = gi < me ? gi : me - 1;
        asrc[i] = hid + (size_t)(off + ri) * FDIM + (lane & 7) * 8;
        bsrc[i] = w2t + ((size_t)e * CDIM + n0 + row) * FDIM + (lane & 7) * 8;
    }

    f32x4 acc[4][4] = {};

#pragma unroll
    for (int i = 0; i < 4; i++) {
        gload16(asrc[i], &smem[0][0][(i * 256 + wv * 64) * 8]);
        gload16(bsrc[i], &smem[0][1][(i * 256 + wv * 64) * 8]);
    }
    __syncthreads();

    int cur = 0;
    for (int kt = 0; kt < NKT; kt++) {
        if (kt + 1 < NKT) {
            const int k1 = (kt + 1) * BK;
#pragma unroll
            for (int i = 0; i < 4; i++) {
                gload16(asrc[i] + k1, &smem[cur ^ 1][0][(i * 256 + wv * 64) * 8]);
                gload16(bsrc[i] + k1, &smem[cur ^ 1][1][(i * 256 + wv * 64) * 8]);
            }
        }
#pragma unroll
        for (int ks = 0; ks < 2; ks++) {
            short8 af[4], bfv[4];
#pragma unroll
            for (int m = 0; m < 4; m++)
                af[m] = *(const short8*)&smem[cur][0][(wr * 64 + m * 16 + fr) * BK + ks * 32 + fq * 8];
#pragma unroll
            for (int n = 0; n < 4; n++)
                bfv[n] = *(const short8*)&smem[cur][1][(wc * 64 + n * 16 + fr) * BK + ks * 32 + fq * 8];
#pragma unroll
            for (int m = 0; m < 4; m++)
#pragma unroll
                for (int n = 0; n < 4; n++)
                    acc[m][n] = __builtin_amdgcn_mfma_f32_16x16x32_bf16(
                        af[m], bfv[n], acc[m][n], 0, 0, 0);
        }
        __syncthreads();
        cur ^= 1;
    }

    if (ybuf) {
        __hip_bfloat16 (*Cl)[BN] = reinterpret_cast<__hip_bfloat16(*)[BN]>(&smem[0][0][0]);
#pragma unroll
        for (int m = 0; m < 4; m++)
#pragma unroll
            for (int n = 0; n < 4; n++)
#pragma unroll
                for (int r = 0; r < 4; r++) {
                    int il = wr * 64 + m * 16 + fq * 4 + r;
                    Cl[il][wc * 64 + n * 16 + fr] =
                        __float2bfloat16(rwt[il] * acc[m][n][r]);
                }
        __syncthreads();
#pragma unroll
        for (int i = 0; i < 8; i++) {
            int chunk = i * 256 + tid;
            int row = chunk >> 4, c8 = (chunk & 15) * 8;
            int gi = m0 + row;
            if (gi < me)
                *(short8*)(ybuf + (size_t)(off + gi) * CDIM + n0 + c8) =
                    *(const short8*)&Cl[row][c8];
        }
    } else {
#pragma unroll
        for (int m = 0; m < 4; m++)
#pragma unroll
            for (int n = 0; n < 4; n++)
#pragma unroll
                for (int r = 0; r < 4; r++) {
                    int il = wr * 64 + m * 16 + fq * 4 + r;
                    int gi = m0 + il;
                    if (gi < me)
                        atomicAdd(&out[(size_t)rtok[il] * CDIM + n0 + wc * 64 + n * 16 + fr],
                                  rwt[il] * acc[m][n][r]);
                }
    }
}

// ---------------- gather: out[n] = y[slot0] + y[slot1] ----------------
__global__ __launch_bounds__(256) void gather_out(
    const __hip_bfloat16* __restrict__ yb, const int* __restrict__ slot,
    float* __restrict__ out)
{
    for (int n = blockIdx.x; n < NTOK; n += gridDim.x) {
        const int s0 = slot[2 * n], s1 = slot[2 * n + 1];
        const int c = threadIdx.x * 4;
        U4 a, b;
        a.u = *(const unsigned long long*)(yb + (size_t)s0 * CDIM + c);
        b.u = *(const unsigned long long*)(yb + (size_t)s1 * CDIM + c);
        float4 o;
        o.x = bf2f(a.s[0]) + bf2f(b.s[0]);
        o.y = bf2f(a.s[1]) + bf2f(b.s[1]);
        o.z = bf2f(a.s[2]) + bf2f(b.s[2]);
        o.w = bf2f(a.s[3]) + bf2f(b.s[3]);
        *(float4*)(out + (size_t)n * CDIM + c) = o;
    }
}

// ---------------- launch ----------------
extern "C" void kernel_launch(void* const* d_in, const int* in_sizes, int n_in,
                              void* d_out, int out_size, void* d_ws, size_t ws_size,
                              hipStream_t stream)
{
    const float* x  = (const float*)d_in[0];
    const float* rw = (const float*)d_in[1];
    const float* w1 = (const float*)d_in[2];
    const float* w2 = (const float*)d_in[3];
    float* out = (float*)d_out;
    char* ws = (char*)d_ws;

    int* cnt  = (int*)ws;                             // 8 counters, 64B stride
    int* offs = (int*)(ws + 1024);
    int* wl   = (int*)(ws + 2048);
    int* rows = (int*)(ws + 4096);                    // [E][NTOK]
    float* wts = (float*)(ws + 4096 + NEXP * NTOK * 4);
    int* slot = (int*)(ws + 4096 + 2 * NEXP * NTOK * 4);  // [NTOK][2]
    __hip_bfloat16* xb  = (__hip_bfloat16*)(ws + (1u << 20));    // 16 MB
    __hip_bfloat16* w1t = (__hip_bfloat16*)(ws + (17u << 20));   // 16 MB
    __hip_bfloat16* hid = (__hip_bfloat16*)(ws + (33u << 20));   // 32 MB
    __hip_bfloat16* w2t = w1t;  // w1t dead after gemm1
    const bool big = ws_size >= ((size_t)98 << 20);
    __hip_bfloat16* ybuf = big ? (__hip_bfloat16*)(ws + (65u << 20)) : nullptr; // 32 MB

    hipMemsetAsync(cnt, 0, 1024, stream);
    if (!big)
        hipMemsetAsync(d_out, 0, (size_t)out_size * sizeof(float), stream);

    router_kernel<<<NTOK / 16, 256, 0, stream>>>(x, rw, xb, cnt, rows, wts);
    scan_offsets<<<1, 64, 0, stream>>>(cnt, offs, wl);
    build_slots<<<dim3(NTOK / 256, NEXP), 256, 0, stream>>>(cnt, offs, rows, slot);
    transpose_conv<<<dim3(32, 32, NEXP), 256, 0, stream>>>(w1, w1t);
    moe_gemm1<<<NWG, 256, 0, stream>>>(xb, w1t, cnt, offs, wl, rows, hid);
    transpose_conv<<<dim3(32, 32, NEXP), 256, 0, stream>>>(w2, w2t);
    moe_gemm2<<<NWG, 256, 0, stream>>>(hid, w2t, cnt, offs, wl, rows, wts, ybuf, out);
    if (big)
        gather_out<<<2048, 256, 0, stream>>>(ybuf, slot, out);
}

// Round 6
// 165.250 us; speedup vs baseline: 3.0606x; 1.1393x over previous
//
#include <hip/hip_runtime.h>
#include <hip/hip_bf16.h>

#define NTOK 8192
#define CDIM 1024
#define FDIM 1024
#define NEXP 8
#define BM 128
#define BN 128
#define BK 64
#define NKT (CDIM / BK)   // 16 K-steps
#define MAXT 136          // sum ceil(me/BM) <= 2*NTOK/BM + NEXP
#define NWG (8 * MAXT)    // 1088 = 8 XCD chunks x 136

typedef __attribute__((ext_vector_type(8))) short short8;
typedef __attribute__((ext_vector_type(4))) float f32x4;

union Pack4 { __hip_bfloat16 h[4]; unsigned long long v; };
union U4 { unsigned long long u; unsigned short s[4]; };

typedef const unsigned int __attribute__((address_space(1)))* gas_ptr;
typedef unsigned int __attribute__((address_space(3)))* las_ptr;

__device__ __forceinline__ void gload16(const void* g, void* l) {
    __builtin_amdgcn_global_load_lds(
        (gas_ptr)(unsigned long long)g,
        (las_ptr)(unsigned int)(unsigned long long)l,
        16, 0, 0);
}

__device__ __forceinline__ float bf2f(unsigned short v) {
    unsigned int t = (unsigned int)v << 16;
    return __uint_as_float(t);
}

// ------- router: fused x->bf16 convert + logits + top-2 scatter (rank in bit16) -------
__global__ __launch_bounds__(256) void router_kernel(
    const float* __restrict__ x, const float* __restrict__ rw,
    __hip_bfloat16* __restrict__ xb,
    int* __restrict__ cnt, int* __restrict__ rows, float* __restrict__ wts)
{
    __shared__ int lcnt[NEXP];
    __shared__ int lt[NEXP][32];
    __shared__ float lw[NEXP][32];
    __shared__ int base[NEXP];
    const int tid = threadIdx.x;
    const int wv = tid >> 6, lane = tid & 63;
    if (tid < NEXP) lcnt[tid] = 0;
    __syncthreads();

    for (int tt = 0; tt < 4; tt++) {
        const int n = blockIdx.x * 16 + wv * 4 + tt;
        float acc[NEXP];
#pragma unroll
        for (int e = 0; e < NEXP; e++) acc[e] = 0.f;
#pragma unroll
        for (int c0 = 0; c0 < CDIM; c0 += 256) {
            const size_t o = (size_t)n * CDIM + c0 + lane * 4;
            float4 xv = *(const float4*)(x + o);
            Pack4 p4;
            p4.h[0] = __float2bfloat16(xv.x); p4.h[1] = __float2bfloat16(xv.y);
            p4.h[2] = __float2bfloat16(xv.z); p4.h[3] = __float2bfloat16(xv.w);
            *(unsigned long long*)(xb + o) = p4.v;
#pragma unroll
            for (int e = 0; e < NEXP; e++) {
                float4 w4 = *(const float4*)&rw[e * CDIM + c0 + lane * 4];
                acc[e] += xv.x * w4.x + xv.y * w4.y + xv.z * w4.z + xv.w * w4.w;
            }
        }
#pragma unroll
        for (int e = 0; e < NEXP; e++) {
#pragma unroll
            for (int s = 32; s > 0; s >>= 1) acc[e] += __shfl_xor(acc[e], s);
        }
        if (lane == 0) {
            float mx = acc[0];
#pragma unroll
            for (int e = 1; e < NEXP; e++) mx = fmaxf(mx, acc[e]);
            float p[NEXP], se = 0.f;
#pragma unroll
            for (int e = 0; e < NEXP; e++) { p[e] = __expf(acc[e] - mx); se += p[e]; }
            float inv = 1.f / se;
            int i0 = 0;
#pragma unroll
            for (int e = 1; e < NEXP; e++) if (p[e] > p[i0]) i0 = e;
            int i1 = (i0 == 0) ? 1 : 0;
#pragma unroll
            for (int e = 0; e < NEXP; e++) if (e != i0 && p[e] > p[i1]) i1 = e;
            int p0 = atomicAdd(&lcnt[i0], 1);
            lt[i0][p0] = n;
            lw[i0][p0] = p[i0] * inv;
            int p1 = atomicAdd(&lcnt[i1], 1);
            lt[i1][p1] = n | (1 << 16);
            lw[i1][p1] = p[i1] * inv;
        }
    }
    __syncthreads();
    if (tid < NEXP) base[tid] = atomicAdd(&cnt[tid * 16], lcnt[tid]);
    __syncthreads();
#pragma unroll
    for (int e = 0; e < NEXP; e++) {
        for (int i = tid; i < lcnt[e]; i += 256) {
            rows[e * NTOK + base[e] + i] = lt[e][i];
            wts [e * NTOK + base[e] + i] = lw[e][i];
        }
    }
}

// --------- scan: expert offsets + dense m-tile worklist ---------
__global__ void scan_offsets(const int* __restrict__ cnt, int* __restrict__ offs,
                             int* __restrict__ wl)
{
    if (threadIdx.x == 0) {
        int s = 0, t = 0;
        for (int e = 0; e < NEXP; e++) {
            int me = cnt[e * 16];
            offs[e] = s; s += me;
            for (int m0 = 0; m0 < me; m0 += BM) {
                wl[1 + 2 * t] = e; wl[2 + 2 * t] = m0; t++;
            }
        }
        wl[0] = t;
    }
}

// --------- invert: slot[2n + rank] = off[e] + i ---------
__global__ __launch_bounds__(256) void build_slots(
    const int* __restrict__ cnt, const int* __restrict__ offs,
    const int* __restrict__ rows, int* __restrict__ slot)
{
    const int e = blockIdx.y;
    const int i = blockIdx.x * 256 + threadIdx.x;
    if (i < cnt[e * 16]) {
        int p = rows[e * NTOK + i];
        slot[2 * (p & 0xFFFF) + (p >> 16)] = offs[e] + i;
    }
}

// ------------- transpose + fp32->bf16: src [E][R][C] -> dst [E][C][R] -------------
__global__ __launch_bounds__(256) void transpose_conv(
    const float* __restrict__ src, __hip_bfloat16* __restrict__ dst)
{
    __shared__ float t[32][33];
    const int e = blockIdx.z;
    const int r0 = blockIdx.x * 32, c0 = blockIdx.y * 32;
    const int tid = threadIdx.x;
    const int rr = tid >> 3;
    const int cc = (tid & 7) * 4;
    const float* p = src + ((size_t)e * 1024 + r0 + rr) * 1024 + c0 + cc;
    float4 v = *(const float4*)p;
    t[rr][cc] = v.x; t[rr][cc + 1] = v.y; t[rr][cc + 2] = v.z; t[rr][cc + 3] = v.w;
    __syncthreads();
    const int cr = tid >> 3;
    const int rc = (tid & 7) * 4;
    Pack4 o;
#pragma unroll
    for (int j = 0; j < 4; j++) o.h[j] = __float2bfloat16(t[rc + j][cr]);
    *(unsigned long long*)(dst + ((size_t)e * 1024 + c0 + cr) * 1024 + r0 + rc) = o.v;
}

// ---------------- GEMM1: hid = relu(Xb[rows] @ w1t^T), dbuf + T2 swizzle ----------------
// LDS[row][j] holds global[row][j ^ (row&7)] (16B chunks); read applies same XOR.
__global__ __launch_bounds__(256, 2) void moe_gemm1(
    const __hip_bfloat16* __restrict__ xb, const __hip_bfloat16* __restrict__ w1t,
    const int* __restrict__ cnt, const int* __restrict__ offs,
    const int* __restrict__ wl, const int* __restrict__ rows,
    __hip_bfloat16* __restrict__ hid)
{
    const int bid = blockIdx.x;
    const int wid = (bid & 7) * MAXT + (bid >> 3);   // XCD-chunked
    const int t = wid >> 3;
    if (t >= wl[0]) return;
    const int n0 = (wid & 7) * BN;
    const int e = wl[1 + 2 * t], m0 = wl[2 + 2 * t];
    const int me = cnt[e * 16], off = offs[e];
    const int tid = threadIdx.x;
    const int lane = tid & 63, wv = tid >> 6;
    const int wr = wv >> 1, wc = wv & 1;
    const int fr = lane & 15, fq = lane >> 4;
    const int fx = fr & 7;                 // read-side swizzle key (row&7)

    __shared__ alignas(16) __hip_bfloat16 smem[2][2][BM * BK];

    // staging chunk for lane: row = i*32 + wv*8 + (lane>>3); row&7 == lane>>3.
    // pre-swizzled global source chunk = (lane&7) ^ (lane>>3)  [16B units]
    const int swz8 = (((lane & 7) ^ (lane >> 3))) * 8;   // bf16 elems
    const __hip_bfloat16* asrc[4];
    const __hip_bfloat16* bsrc[4];
#pragma unroll
    for (int i = 0; i < 4; i++) {
        int row = i * 32 + wv * 8 + (lane >> 3);
        int gi = m0 + row;
        int ri = gi < me ? gi : me - 1;
        int tok = rows[e * NTOK + ri] & 0xFFFF;
        asrc[i] = xb + (size_t)tok * CDIM + swz8;
        bsrc[i] = w1t + ((size_t)e * FDIM + n0 + row) * CDIM + swz8;
    }

    f32x4 acc[4][4] = {};

#pragma unroll
    for (int i = 0; i < 4; i++) {
        gload16(asrc[i], &smem[0][0][(i * 256 + wv * 64) * 8]);
        gload16(bsrc[i], &smem[0][1][(i * 256 + wv * 64) * 8]);
    }
    __syncthreads();

    int cur = 0;
    for (int kt = 0; kt < NKT; kt++) {
        if (kt + 1 < NKT) {
            const int k1 = (kt + 1) * BK;
#pragma unroll
            for (int i = 0; i < 4; i++) {
                gload16(asrc[i] + k1, &smem[cur ^ 1][0][(i * 256 + wv * 64) * 8]);
                gload16(bsrc[i] + k1, &smem[cur ^ 1][1][(i * 256 + wv * 64) * 8]);
            }
        }
#pragma unroll
        for (int ks = 0; ks < 2; ks++) {
            short8 af[4], bfv[4];
#pragma unroll
            for (int m = 0; m < 4; m++)
                af[m] = *(const short8*)&smem[cur][0][
                    (wr * 64 + m * 16 + fr) * BK + (((ks * 4 + fq) ^ fx) * 8)];
#pragma unroll
            for (int n = 0; n < 4; n++)
                bfv[n] = *(const short8*)&smem[cur][1][
                    (wc * 64 + n * 16 + fr) * BK + (((ks * 4 + fq) ^ fx) * 8)];
#pragma unroll
            for (int m = 0; m < 4; m++)
#pragma unroll
                for (int n = 0; n < 4; n++)
                    acc[m][n] = __builtin_amdgcn_mfma_f32_16x16x32_bf16(
                        af[m], bfv[n], acc[m][n], 0, 0, 0);
        }
        __syncthreads();
        cur ^= 1;
    }

    // epilogue: C through LDS, coalesced full-line stores
    __hip_bfloat16 (*Cl)[BN] = reinterpret_cast<__hip_bfloat16(*)[BN]>(&smem[0][0][0]);
#pragma unroll
    for (int m = 0; m < 4; m++)
#pragma unroll
        for (int n = 0; n < 4; n++)
#pragma unroll
            for (int r = 0; r < 4; r++) {
                int il = wr * 64 + m * 16 + fq * 4 + r;
                float v = acc[m][n][r];
                Cl[il][wc * 64 + n * 16 + fr] = __float2bfloat16(v > 0.f ? v : 0.f);
            }
    __syncthreads();
#pragma unroll
    for (int i = 0; i < 8; i++) {
        int chunk = i * 256 + tid;
        int row = chunk >> 4, c8 = (chunk & 15) * 8;
        int gi = m0 + row;
        if (gi < me)
            *(short8*)(hid + (size_t)(off + gi) * FDIM + n0 + c8) =
                *(const short8*)&Cl[row][c8];
    }
}

// ------- GEMM2: ybuf[slot] = wt * (hid @ w2t^T), dbuf + T2 swizzle -------
__global__ __launch_bounds__(256, 2) void moe_gemm2(
    const __hip_bfloat16* __restrict__ hid, const __hip_bfloat16* __restrict__ w2t,
    const int* __restrict__ cnt, const int* __restrict__ offs,
    const int* __restrict__ wl, const int* __restrict__ rows,
    const float* __restrict__ wts, __hip_bfloat16* __restrict__ ybuf,
    float* __restrict__ out)
{
    const int bid = blockIdx.x;
    const int wid = (bid & 7) * MAXT + (bid >> 3);
    const int t = wid >> 3;
    if (t >= wl[0]) return;
    const int n0 = (wid & 7) * BN;
    const int e = wl[1 + 2 * t], m0 = wl[2 + 2 * t];
    const int me = cnt[e * 16], off = offs[e];
    const int tid = threadIdx.x;
    const int lane = tid & 63, wv = tid >> 6;
    const int wr = wv >> 1, wc = wv & 1;
    const int fr = lane & 15, fq = lane >> 4;
    const int fx = fr & 7;

    __shared__ alignas(16) __hip_bfloat16 smem[2][2][BM * BK];
    __shared__ int rtok[BM];
    __shared__ float rwt[BM];

    if (tid < BM) {
        int gi = m0 + tid;
        int ri = gi < me ? gi : me - 1;
        rtok[tid] = rows[e * NTOK + ri] & 0xFFFF;
        rwt[tid] = gi < me ? wts[e * NTOK + ri] : 0.f;
    }

    const int swz8 = (((lane & 7) ^ (lane >> 3))) * 8;
    const __hip_bfloat16* asrc[4];
    const __hip_bfloat16* bsrc[4];
#pragma unroll
    for (int i = 0; i < 4; i++) {
        int row = i * 32 + wv * 8 + (lane >> 3);
        int gi = m0 + row;
        int ri = gi < me ? gi : me - 1;
        asrc[i] = hid + (size_t)(off + ri) * FDIM + swz8;
        bsrc[i] = w2t + ((size_t)e * CDIM + n0 + row) * FDIM + swz8;
    }

    f32x4 acc[4][4] = {};

#pragma unroll
    for (int i = 0; i < 4; i++) {
        gload16(asrc[i], &smem[0][0][(i * 256 + wv * 64) * 8]);
        gload16(bsrc[i], &smem[0][1][(i * 256 + wv * 64) * 8]);
    }
    __syncthreads();

    int cur = 0;
    for (int kt = 0; kt < NKT; kt++) {
        if (kt + 1 < NKT) {
            const int k1 = (kt + 1) * BK;
#pragma unroll
            for (int i = 0; i < 4; i++) {
                gload16(asrc[i] + k1, &smem[cur ^ 1][0][(i * 256 + wv * 64) * 8]);
                gload16(bsrc[i] + k1, &smem[cur ^ 1][1][(i * 256 + wv * 64) * 8]);
            }
        }
#pragma unroll
        for (int ks = 0; ks < 2; ks++) {
            short8 af[4], bfv[4];
#pragma unroll
            for (int m = 0; m < 4; m++)
                af[m] = *(const short8*)&smem[cur][0][
                    (wr * 64 + m * 16 + fr) * BK + (((ks * 4 + fq) ^ fx) * 8)];
#pragma unroll
            for (int n = 0; n < 4; n++)
                bfv[n] = *(const short8*)&smem[cur][1][
                    (wc * 64 + n * 16 + fr) * BK + (((ks * 4 + fq) ^ fx) * 8)];
#pragma unroll
            for (int m = 0; m < 4; m++)
#pragma unroll
                for (int n = 0; n < 4; n++)
                    acc[m][n] = __builtin_amdgcn_mfma_f32_16x16x32_bf16(
                        af[m], bfv[n], acc[m][n], 0, 0, 0);
        }
        __syncthreads();
        cur ^= 1;
    }

    if (ybuf) {
        __hip_bfloat16 (*Cl)[BN] = reinterpret_cast<__hip_bfloat16(*)[BN]>(&smem[0][0][0]);
#pragma unroll
        for (int m = 0; m < 4; m++)
#pragma unroll
            for (int n = 0; n < 4; n++)
#pragma unroll
                for (int r = 0; r < 4; r++) {
                    int il = wr * 64 + m * 16 + fq * 4 + r;
                    Cl[il][wc * 64 + n * 16 + fr] =
                        __float2bfloat16(rwt[il] * acc[m][n][r]);
                }
        __syncthreads();
#pragma unroll
        for (int i = 0; i < 8; i++) {
            int chunk = i * 256 + tid;
            int row = chunk >> 4, c8 = (chunk & 15) * 8;
            int gi = m0 + row;
            if (gi < me)
                *(short8*)(ybuf + (size_t)(off + gi) * CDIM + n0 + c8) =
                    *(const short8*)&Cl[row][c8];
        }
    } else {
#pragma unroll
        for (int m = 0; m < 4; m++)
#pragma unroll
            for (int n = 0; n < 4; n++)
#pragma unroll
                for (int r = 0; r < 4; r++) {
                    int il = wr * 64 + m * 16 + fq * 4 + r;
                    int gi = m0 + il;
                    if (gi < me)
                        atomicAdd(&out[(size_t)rtok[il] * CDIM + n0 + wc * 64 + n * 16 + fr],
                                  rwt[il] * acc[m][n][r]);
                }
    }
}

// ---------------- gather: out[n] = y[slot0] + y[slot1] ----------------
__global__ __launch_bounds__(256) void gather_out(
    const __hip_bfloat16* __restrict__ yb, const int* __restrict__ slot,
    float* __restrict__ out)
{
    for (int n = blockIdx.x; n < NTOK; n += gridDim.x) {
        const int s0 = slot[2 * n], s1 = slot[2 * n + 1];
        const int c = threadIdx.x * 4;
        U4 a, b;
        a.u = *(const unsigned long long*)(yb + (size_t)s0 * CDIM + c);
        b.u = *(const unsigned long long*)(yb + (size_t)s1 * CDIM + c);
        float4 o;
        o.x = bf2f(a.s[0]) + bf2f(b.s[0]);
        o.y = bf2f(a.s[1]) + bf2f(b.s[1]);
        o.z = bf2f(a.s[2]) + bf2f(b.s[2]);
        o.w = bf2f(a.s[3]) + bf2f(b.s[3]);
        *(float4*)(out + (size_t)n * CDIM + c) = o;
    }
}

// ---------------- launch ----------------
extern "C" void kernel_launch(void* const* d_in, const int* in_sizes, int n_in,
                              void* d_out, int out_size, void* d_ws, size_t ws_size,
                              hipStream_t stream)
{
    const float* x  = (const float*)d_in[0];
    const float* rw = (const float*)d_in[1];
    const float* w1 = (const float*)d_in[2];
    const float* w2 = (const float*)d_in[3];
    float* out = (float*)d_out;
    char* ws = (char*)d_ws;

    int* cnt  = (int*)ws;                             // 8 counters, 64B stride
    int* offs = (int*)(ws + 1024);
    int* wl   = (int*)(ws + 2048);
    int* rows = (int*)(ws + 4096);                    // [E][NTOK]
    float* wts = (float*)(ws + 4096 + NEXP * NTOK * 4);
    int* slot = (int*)(ws + 4096 + 2 * NEXP * NTOK * 4);  // [NTOK][2]
    __hip_bfloat16* xb  = (__hip_bfloat16*)(ws + (1u << 20));    // 16 MB
    __hip_bfloat16* w1t = (__hip_bfloat16*)(ws + (17u << 20));   // 16 MB
    __hip_bfloat16* hid = (__hip_bfloat16*)(ws + (33u << 20));   // 32 MB
    __hip_bfloat16* w2t = w1t;  // w1t dead after gemm1
    const bool big = ws_size >= ((size_t)98 << 20);
    __hip_bfloat16* ybuf = big ? (__hip_bfloat16*)(ws + (65u << 20)) : nullptr; // 32 MB

    hipMemsetAsync(cnt, 0, 1024, stream);
    if (!big)
        hipMemsetAsync(d_out, 0, (size_t)out_size * sizeof(float), stream);

    router_kernel<<<NTOK / 16, 256, 0, stream>>>(x, rw, xb, cnt, rows, wts);
    scan_offsets<<<1, 64, 0, stream>>>(cnt, offs, wl);
    build_slots<<<dim3(NTOK / 256, NEXP), 256, 0, stream>>>(cnt, offs, rows, slot);
    transpose_conv<<<dim3(32, 32, NEXP), 256, 0, stream>>>(w1, w1t);
    moe_gemm1<<<NWG, 256, 0, stream>>>(xb, w1t, cnt, offs, wl, rows, hid);
    transpose_conv<<<dim3(32, 32, NEXP), 256, 0, stream>>>(w2, w2t);
    moe_gemm2<<<NWG, 256, 0, stream>>>(hid, w2t, cnt, offs, wl, rows, wts, ybuf, out);
    if (big)
        gather_out<<<2048, 256, 0, stream>>>(ybuf, slot, out);
}